// Round 12
// baseline (25.210 us; speedup 1.0000x reference)
//
#include <hip/hip_runtime.h>
#include <math.h>

#define NTOK 256
#define DD 16
#define BDIM 512

typedef short short8 __attribute__((ext_vector_type(8)));
typedef float f32x16 __attribute__((ext_vector_type(16)));
typedef unsigned int u32;
typedef unsigned long long u64;

__device__ __forceinline__ u32 f2bf(float f) {
    u32 u = __float_as_uint(f);
    u += 0x7FFFu + ((u >> 16) & 1u);
    return u >> 16;
}
struct U128 { u64 a, b; };
__device__ __forceinline__ short8 ld8(const unsigned short* p) {
    U128 t;
    t.a = *(const u64*)(p);
    t.b = *(const u64*)(p + 4);
    return __builtin_bit_cast(short8, t);
}
// pack 16 f32 (reg t -> k-offset pat(t,hi)=(t&3)+8*(t>>2)+4*hi) into two
// fragment short8s with k = 8*hi+e (f0: k 0..15, f1: k 16..31). HW-validated R3/R4/R6.
__device__ __forceinline__ void pack_swap16(f32x16 p, short8& f0, short8& f1) {
    u32 W00, W01, W10, W11, W20, W21, W30, W31;
    asm("v_cvt_pk_bf16_f32 %0, %1, %2" : "=v"(W00) : "v"(p[0]),  "v"(p[1]));
    asm("v_cvt_pk_bf16_f32 %0, %1, %2" : "=v"(W01) : "v"(p[2]),  "v"(p[3]));
    asm("v_cvt_pk_bf16_f32 %0, %1, %2" : "=v"(W10) : "v"(p[4]),  "v"(p[5]));
    asm("v_cvt_pk_bf16_f32 %0, %1, %2" : "=v"(W11) : "v"(p[6]),  "v"(p[7]));
    asm("v_cvt_pk_bf16_f32 %0, %1, %2" : "=v"(W20) : "v"(p[8]),  "v"(p[9]));
    asm("v_cvt_pk_bf16_f32 %0, %1, %2" : "=v"(W21) : "v"(p[10]), "v"(p[11]));
    asm("v_cvt_pk_bf16_f32 %0, %1, %2" : "=v"(W30) : "v"(p[12]), "v"(p[13]));
    asm("v_cvt_pk_bf16_f32 %0, %1, %2" : "=v"(W31) : "v"(p[14]), "v"(p[15]));
    asm("v_permlane32_swap_b32 %0, %1" : "+v"(W00), "+v"(W10));
    asm("v_permlane32_swap_b32 %0, %1" : "+v"(W01), "+v"(W11));
    asm("v_permlane32_swap_b32 %0, %1" : "+v"(W20), "+v"(W30));
    asm("v_permlane32_swap_b32 %0, %1" : "+v"(W21), "+v"(W31));
    struct { u32 x, y, z, w; } i0{W00, W01, W10, W11}, i1{W20, W21, W30, W31};
    f0 = __builtin_bit_cast(short8, i0);
    f1 = __builtin_bit_cast(short8, i1);
}
// exact-GELU via Abramowitz-Stegun 7.1.26 erf (|err| <= 1.5e-7)
__device__ __forceinline__ float gelu_erf(float v) {
    float xx = v * 0.70710678118654752f;
    float ax = fabsf(xx);
    float t = __builtin_amdgcn_rcpf(__builtin_fmaf(0.3275911f, ax, 1.0f));
    float poly = t * (0.254829592f + t * (-0.284496736f + t * (1.421413741f
               + t * (-1.453152027f + t * 1.061405429f))));
    float r = 1.0f - poly * __expf(-ax * ax);
    float e = copysignf(r, xx);
    return 0.5f * v * (1.0f + e);
}

__global__ __launch_bounds__(BDIM, 8) void qab_kernel(
    const float* __restrict__ x,
    const float* __restrict__ ln1_g, const float* __restrict__ ln1_b,
    const float* __restrict__ angles,
    const float* __restrict__ ln2_g, const float* __restrict__ ln2_b,
    const float* __restrict__ w1, const float* __restrict__ b1,
    const float* __restrict__ w2, const float* __restrict__ b2,
    float* __restrict__ out)
{
    __shared__ alignas(16) unsigned short a_bf[NTOK][20];   // amplitudes bf16; later O-partials (f32)
    __shared__ alignas(16) unsigned short wa_bf[NTOK][20];  // Wa bf16
    __shared__ alignas(16) unsigned short vxT[17][268];     // |Wa|^T + ones row
    __shared__ alignas(16) unsigned short w1tb[64][20];     // w1^T bf16 [k][e]
    __shared__ alignas(16) unsigned short w2tb[16][68];     // w2^T bf16 [d][k]
    __shared__ alignas(16) float b1_lds[64];
    __shared__ alignas(16) float ln2g_lds[DD];
    __shared__ alignas(16) float ln2b_lds[DD];
    __shared__ alignas(16) float b2_lds[DD];

    const int bb    = blockIdx.x;
    const int b     = bb >> 1;          // batch
    const int half  = bb & 1;           // strip group (0: strips 0-3, 1: 4-7)
    const int tid   = threadIdx.x;
    const int r     = tid & (NTOK - 1);
    const int q     = tid >> 8;
    const int w     = tid >> 6;         // wave 0..7
    const int strip = half * 4 + (w >> 1);
    const int jh    = w & 1;            // j-half: even wave jt 0-3, odd jt 4-7
    const int l31   = tid & 31;
    const int hi    = (tid >> 5) & 1;
    const int lane  = tid & 63;

    // residual-x loads (token = my strip lane-row); used by even waves in P3
    const float* xres = x + ((size_t)b * NTOK + 32 * strip + l31) * DD;
    const float4 xra = *(const float4*)(xres + 4 * hi);
    const float4 xrb = *(const float4*)(xres + 8 + 4 * hi);

    f32x16 zc;
    #pragma unroll
    for (int t = 0; t < 16; ++t) zc[t] = 0.0f;

    // ---------------- P0: LN1 + amp chain (ALL threads; row r) ----------------
    float amp[DD];
    {
        const float* xrow = x + ((size_t)b * NTOK + r) * DD;
        float xr[DD];
        #pragma unroll
        for (int qq = 0; qq < 4; ++qq) {
            float4 v = ((const float4*)xrow)[qq];
            xr[4*qq+0] = v.x; xr[4*qq+1] = v.y; xr[4*qq+2] = v.z; xr[4*qq+3] = v.w;
        }
        float mu = 0.0f;
        #pragma unroll
        for (int d = 0; d < DD; ++d) mu += xr[d];
        mu *= (1.0f / DD);
        float var = 0.0f;
        #pragma unroll
        for (int d = 0; d < DD; ++d) { float dv = xr[d] - mu; var += dv * dv; }
        var *= (1.0f / DD);
        float rs = 1.0f / sqrtf(var + 1e-5f);
        float inp[DD];
        #pragma unroll
        for (int d = 0; d < DD; ++d)
            inp[d] = ((xr[d] - mu) * rs * ln1_g[d] + ln1_b[d]) * 0.5f;

        // Spherical decomposition reconstructs its input; track prefix^2 only.
        float P = 1.0f;
        #pragma unroll
        for (int i = 0; i < DD - 1; ++i) {
            float v = inp[i];
            float v2 = v * v;
            bool ok = v2 <= P;
            amp[i] = ok ? v : __builtin_amdgcn_sqrtf(P);
            P = ok ? __builtin_fmaf(-v, v, P) : 0.0f;
        }
        amp[DD - 1] = __builtin_amdgcn_sqrtf(P);
    }

    if (q == 0) {
        // ---- write a_bf + stage weights/consts ----
        u32 aw[8];
        #pragma unroll
        for (int k = 0; k < 8; ++k)
            asm("v_cvt_pk_bf16_f32 %0, %1, %2" : "=v"(aw[k]) : "v"(amp[2*k]), "v"(amp[2*k+1]));
        *(u64*)&a_bf[r][0]  = (u64)aw[0] | ((u64)aw[1] << 32);
        *(u64*)&a_bf[r][4]  = (u64)aw[2] | ((u64)aw[3] << 32);
        *(u64*)&a_bf[r][8]  = (u64)aw[4] | ((u64)aw[5] << 32);
        *(u64*)&a_bf[r][12] = (u64)aw[6] | ((u64)aw[7] << 32);
        for (int i = r; i < 64 * DD; i += NTOK) {
            w1tb[i & 63][i >> 6] = (unsigned short)f2bf(w1[i]);   // w1^T
            w2tb[i & 15][i >> 4] = (unsigned short)f2bf(w2[i]);   // w2^T
        }
        if (r >= 128 && r < 192) b1_lds[r - 128] = b1[r - 128];
        if (r >= 192 && r < 208) ln2g_lds[r - 192] = ln2_g[r - 192];
        if (r >= 208 && r < 224) ln2b_lds[r - 208] = ln2_b[r - 208];
        if (r >= 224 && r < 240) b2_lds[r - 224] = b2[r - 224];
        vxT[16][r] = 0x3F80;   // ones row -> softmax denominator
    } else {
        // ---- Wa = butterfly rotations applied directly to amp (in place) ----
        float sn_l = 0.0f, cs_l = 0.0f;
        if (lane < 32) __sincosf(angles[lane], &sn_l, &cs_l);
        #pragma unroll
        for (int s = 0; s < 4; ++s) {
            const int step = 1 << s;
            #pragma unroll
            for (int p = 0; p < 8; ++p) {
                const int i = ((p >> s) << (s + 1)) | (p & (step - 1));
                const int j = i + step;
                float sn = __shfl(sn_l, s * 8 + p, 64);   // v_readlane broadcast
                float cs = __shfl(cs_l, s * 8 + p, 64);
                float vi = amp[i], vj = amp[j];
                amp[i] =  cs * vi + sn * vj;
                amp[j] = -sn * vi + cs * vj;
            }
        }
        u32 ww[8];
        #pragma unroll
        for (int k = 0; k < 8; ++k)
            asm("v_cvt_pk_bf16_f32 %0, %1, %2" : "=v"(ww[k]) : "v"(amp[2*k]), "v"(amp[2*k+1]));
        *(u64*)&wa_bf[r][0]  = (u64)ww[0] | ((u64)ww[1] << 32);
        *(u64*)&wa_bf[r][4]  = (u64)ww[2] | ((u64)ww[3] << 32);
        *(u64*)&wa_bf[r][8]  = (u64)ww[4] | ((u64)ww[5] << 32);
        *(u64*)&wa_bf[r][12] = (u64)ww[6] | ((u64)ww[7] << 32);
        #pragma unroll
        for (int d = 0; d < DD; ++d)
            vxT[d][r] = (unsigned short)f2bf(fabsf(amp[d]));
    }
    __syncthreads();

    // ---------------- P2: attention over MY j-half (4 of 8 jt) ----------------
    const int ncl = (l31 < 16) ? l31 : 16;   // vx A-frag row clamp (row16 = ones)
    f32x16 Oacc = zc;
    {
        short8 waf = ld8(&wa_bf[32 * strip + l31][8 * hi]);   // B-frag: col i, k = d
        #pragma unroll
        for (int jj = 0; jj < 4; ++jj) {
            const int jt = 4 * jh + jj;
            short8 af = ld8(&a_bf[jt * 32 + l31][8 * hi]);    // A-frag: row j, k = d
            f32x16 S = __builtin_amdgcn_mfma_f32_32x32x16_bf16(af, waf, zc, 0, 0, 0);
            f32x16 pv;
            #pragma unroll
            for (int t = 0; t < 16; ++t) pv[t] = __expf(fabsf(S[t]));  // s in [0,1]
            short8 pb0, pb1;
            pack_swap16(pv, pb0, pb1);                     // B-frags: col i, k = j
            short8 va0 = ld8(&vxT[ncl][jt * 32 + 8 * hi]); // A-frags: row d, k = j
            short8 va1 = ld8(&vxT[ncl][jt * 32 + 16 + 8 * hi]);
            Oacc = __builtin_amdgcn_mfma_f32_32x32x16_bf16(va0, pb0, Oacc, 0, 0, 0);
            Oacc = __builtin_amdgcn_mfma_f32_32x32x16_bf16(va1, pb1, Oacc, 0, 0, 0);
        }
    }

    // ---------------- combine j-halves through (now-dead) a_bf region ---------
    __syncthreads();   // all a_bf/vxT reads complete
    float* part = (float*)a_bf;   // [(w>>1)*64 + l31*2 + hi] slots of 10 f32
    if (jh == 1) {
        float* pr = part + (((w >> 1) * 64) + l31 * 2 + hi) * 10;
        float2 p0; p0.x = Oacc[0]; p0.y = Oacc[1]; *(float2*)&pr[0] = p0;
        float2 p1; p1.x = Oacc[2]; p1.y = Oacc[3]; *(float2*)&pr[2] = p1;
        float2 p2; p2.x = Oacc[4]; p2.y = Oacc[5]; *(float2*)&pr[4] = p2;
        float2 p3; p3.x = Oacc[6]; p3.y = Oacc[7]; *(float2*)&pr[6] = p3;
        pr[8] = Oacc[8];
    }
    __syncthreads();
    if (jh == 1) return;   // odd waves retire; frees SIMD slots (no barriers below)

    {
        const float* pr = part + (((w >> 1) * 64) + l31 * 2 + hi) * 10;
        #pragma unroll
        for (int k = 0; k < 9; ++k) Oacc[k] += pr[k];
    }

    // ---------------- P3: residual + LN2, in-register (lane pairs) ------------
    // Oacc[8] = row 16 (hi=0) / 20 (hi=1); rows 16..31 all = l (clamped ones-row)
    const float rl = 1.0f / Oacc[8];
    float o1[8];
    o1[0] = xra.x + Oacc[0] * rl;  o1[1] = xra.y + Oacc[1] * rl;
    o1[2] = xra.z + Oacc[2] * rl;  o1[3] = xra.w + Oacc[3] * rl;
    o1[4] = xrb.x + Oacc[4] * rl;  o1[5] = xrb.y + Oacc[5] * rl;
    o1[6] = xrb.z + Oacc[6] * rl;  o1[7] = xrb.w + Oacc[7] * rl;

    float s8 = 0.0f;
    #pragma unroll
    for (int t = 0; t < 8; ++t) s8 += o1[t];
    float mu2 = (s8 + __shfl_xor(s8, 32, 64)) * (1.0f / DD);
    float v8 = 0.0f;
    #pragma unroll
    for (int t = 0; t < 8; ++t) { float dv = o1[t] - mu2; v8 += dv * dv; }
    float var2 = (v8 + __shfl_xor(v8, 32, 64)) * (1.0f / DD);
    float rs2 = 1.0f / sqrtf(var2 + 1e-5f);

    const float4 g0v = *(const float4*)&ln2g_lds[4 * hi];
    const float4 g1v = *(const float4*)&ln2g_lds[8 + 4 * hi];
    const float4 bb0 = *(const float4*)&ln2b_lds[4 * hi];
    const float4 bb1 = *(const float4*)&ln2b_lds[8 + 4 * hi];
    float h[8];
    h[0] = (o1[0]-mu2)*rs2*g0v.x + bb0.x;  h[1] = (o1[1]-mu2)*rs2*g0v.y + bb0.y;
    h[2] = (o1[2]-mu2)*rs2*g0v.z + bb0.z;  h[3] = (o1[3]-mu2)*rs2*g0v.w + bb0.w;
    h[4] = (o1[4]-mu2)*rs2*g1v.x + bb1.x;  h[5] = (o1[5]-mu2)*rs2*g1v.y + bb1.y;
    h[6] = (o1[6]-mu2)*rs2*g1v.z + bb1.z;  h[7] = (o1[7]-mu2)*rs2*g1v.w + bb1.w;

    short8 hB;   // B-frag (col = token, k = d)
    {
        u32 w0, w1u, w2u, w3;
        asm("v_cvt_pk_bf16_f32 %0, %1, %2" : "=v"(w0)  : "v"(h[0]), "v"(h[1]));
        asm("v_cvt_pk_bf16_f32 %0, %1, %2" : "=v"(w1u) : "v"(h[2]), "v"(h[3]));
        asm("v_cvt_pk_bf16_f32 %0, %1, %2" : "=v"(w2u) : "v"(h[4]), "v"(h[5]));
        asm("v_cvt_pk_bf16_f32 %0, %1, %2" : "=v"(w3)  : "v"(h[6]), "v"(h[7]));
        asm("s_nop 1\n\tv_permlane32_swap_b32 %0, %1" : "+v"(w0),  "+v"(w2u));
        asm("s_nop 1\n\tv_permlane32_swap_b32 %0, %1" : "+v"(w1u), "+v"(w3));
        struct { u32 x, y, z, w; } hw{w0, w1u, w2u, w3};
        hB = __builtin_bit_cast(short8, hw);
    }

    // ---------------- P4: MLP via MFMA, lane=token orientation ----------------
    const int dcl = (l31 < 15) ? l31 : 15;   // w2 A-frag row clamp
    f32x16 O2 = zc;
    {
        const float4 c0 = *(const float4*)&b2_lds[4 * hi];
        const float4 c1 = *(const float4*)&b2_lds[8 + 4 * hi];
        O2[0] = c0.x; O2[1] = c0.y; O2[2] = c0.z; O2[3] = c0.w;
        O2[4] = c1.x; O2[5] = c1.y; O2[6] = c1.z; O2[7] = c1.w;
    }
    #pragma unroll
    for (int kblk = 0; kblk < 2; ++kblk) {
        f32x16 Hc;
        {
            const float* bp = &b1_lds[32 * kblk];
            const float4 c0 = *(const float4*)(bp + 4 * hi);
            const float4 c1 = *(const float4*)(bp + 8 + 4 * hi);
            const float4 c2 = *(const float4*)(bp + 16 + 4 * hi);
            const float4 c3 = *(const float4*)(bp + 24 + 4 * hi);
            Hc[0]=c0.x; Hc[1]=c0.y; Hc[2]=c0.z; Hc[3]=c0.w;
            Hc[4]=c1.x; Hc[5]=c1.y; Hc[6]=c1.z; Hc[7]=c1.w;
            Hc[8]=c2.x; Hc[9]=c2.y; Hc[10]=c2.z; Hc[11]=c2.w;
            Hc[12]=c3.x; Hc[13]=c3.y; Hc[14]=c3.z; Hc[15]=c3.w;
        }
        short8 w1f = ld8(&w1tb[32 * kblk + l31][8 * hi]);
        f32x16 H = __builtin_amdgcn_mfma_f32_32x32x16_bf16(w1f, hB, Hc, 0, 0, 0);
        f32x16 gv;
        #pragma unroll
        for (int t = 0; t < 16; ++t) gv[t] = gelu_erf(H[t]);
        short8 gb0, gb1;
        pack_swap16(gv, gb0, gb1);
        short8 w2f0 = ld8(&w2tb[dcl][32 * kblk + 8 * hi]);
        short8 w2f1 = ld8(&w2tb[dcl][32 * kblk + 16 + 8 * hi]);
        O2 = __builtin_amdgcn_mfma_f32_32x32x16_bf16(w2f0, gb0, O2, 0, 0, 0);
        O2 = __builtin_amdgcn_mfma_f32_32x32x16_bf16(w2f1, gb1, O2, 0, 0, 0);
    }

    // ---------------- P5: out = o1 + O2 (+b2 already in O2), direct store -----
    {
        float* orow = out + ((size_t)b * NTOK + 32 * strip + l31) * DD;
        float4 oa, ob;
        oa.x = o1[0] + O2[0]; oa.y = o1[1] + O2[1];
        oa.z = o1[2] + O2[2]; oa.w = o1[3] + O2[3];
        ob.x = o1[4] + O2[4]; ob.y = o1[5] + O2[5];
        ob.z = o1[6] + O2[6]; ob.w = o1[7] + O2[7];
        *(float4*)(orow + 4 * hi) = oa;
        *(float4*)(orow + 8 + 4 * hi) = ob;
    }
}

extern "C" void kernel_launch(void* const* d_in, const int* in_sizes, int n_in,
                              void* d_out, int out_size, void* d_ws, size_t ws_size,
                              hipStream_t stream) {
    const float* x     = (const float*)d_in[0];
    const float* ln1_g = (const float*)d_in[1];
    const float* ln1_b = (const float*)d_in[2];
    const float* ang   = (const float*)d_in[3];
    const float* ln2_g = (const float*)d_in[4];
    const float* ln2_b = (const float*)d_in[5];
    const float* w1    = (const float*)d_in[6];
    const float* b1    = (const float*)d_in[7];
    const float* w2    = (const float*)d_in[8];
    const float* b2    = (const float*)d_in[9];
    float* out = (float*)d_out;

    const int B = in_sizes[0] / (NTOK * DD);
    hipLaunchKernelGGL(qab_kernel, dim3(2 * B), dim3(BDIM), 0, stream,
                       x, ln1_g, ln1_b, ang, ln2_g, ln2_b, w1, b1, w2, b2, out);
}

// Round 13
// 24.305 us; speedup vs baseline: 1.0372x; 1.0372x over previous
//
#include <hip/hip_runtime.h>
#include <math.h>

#define NTOK 256
#define DD 16
#define BDIM 1024

typedef short short8 __attribute__((ext_vector_type(8)));
typedef float f32x16 __attribute__((ext_vector_type(16)));
typedef unsigned int u32;
typedef unsigned long long u64;

__device__ __forceinline__ u32 f2bf(float f) {
    u32 u = __float_as_uint(f);
    u += 0x7FFFu + ((u >> 16) & 1u);
    return u >> 16;
}
struct U128 { u64 a, b; };
__device__ __forceinline__ short8 ld8(const unsigned short* p) {
    U128 t;
    t.a = *(const u64*)(p);
    t.b = *(const u64*)(p + 4);
    return __builtin_bit_cast(short8, t);
}
// pack 16 f32 (reg t -> k-offset pat(t,hi)=(t&3)+8*(t>>2)+4*hi) into two
// fragment short8s with k = 8*hi+e (f0: k 0..15, f1: k 16..31). HW-validated R3/R4/R6.
__device__ __forceinline__ void pack_swap16(f32x16 p, short8& f0, short8& f1) {
    u32 W00, W01, W10, W11, W20, W21, W30, W31;
    asm("v_cvt_pk_bf16_f32 %0, %1, %2" : "=v"(W00) : "v"(p[0]),  "v"(p[1]));
    asm("v_cvt_pk_bf16_f32 %0, %1, %2" : "=v"(W01) : "v"(p[2]),  "v"(p[3]));
    asm("v_cvt_pk_bf16_f32 %0, %1, %2" : "=v"(W10) : "v"(p[4]),  "v"(p[5]));
    asm("v_cvt_pk_bf16_f32 %0, %1, %2" : "=v"(W11) : "v"(p[6]),  "v"(p[7]));
    asm("v_cvt_pk_bf16_f32 %0, %1, %2" : "=v"(W20) : "v"(p[8]),  "v"(p[9]));
    asm("v_cvt_pk_bf16_f32 %0, %1, %2" : "=v"(W21) : "v"(p[10]), "v"(p[11]));
    asm("v_cvt_pk_bf16_f32 %0, %1, %2" : "=v"(W30) : "v"(p[12]), "v"(p[13]));
    asm("v_cvt_pk_bf16_f32 %0, %1, %2" : "=v"(W31) : "v"(p[14]), "v"(p[15]));
    asm("v_permlane32_swap_b32 %0, %1" : "+v"(W00), "+v"(W10));
    asm("v_permlane32_swap_b32 %0, %1" : "+v"(W01), "+v"(W11));
    asm("v_permlane32_swap_b32 %0, %1" : "+v"(W20), "+v"(W30));
    asm("v_permlane32_swap_b32 %0, %1" : "+v"(W21), "+v"(W31));
    struct { u32 x, y, z, w; } i0{W00, W01, W10, W11}, i1{W20, W21, W30, W31};
    f0 = __builtin_bit_cast(short8, i0);
    f1 = __builtin_bit_cast(short8, i1);
}
// exact-GELU via Abramowitz-Stegun 7.1.26 erf (|err| <= 1.5e-7)
__device__ __forceinline__ float gelu_erf(float v) {
    float xx = v * 0.70710678118654752f;
    float ax = fabsf(xx);
    float t = __builtin_amdgcn_rcpf(__builtin_fmaf(0.3275911f, ax, 1.0f));
    float poly = t * (0.254829592f + t * (-0.284496736f + t * (1.421413741f
               + t * (-1.453152027f + t * 1.061405429f))));
    float r = 1.0f - poly * __expf(-ax * ax);
    float e = copysignf(r, xx);
    return 0.5f * v * (1.0f + e);
}

__global__ __launch_bounds__(BDIM, 8) void qab_kernel(
    const float* __restrict__ x,
    const float* __restrict__ ln1_g, const float* __restrict__ ln1_b,
    const float* __restrict__ angles,
    const float* __restrict__ ln2_g, const float* __restrict__ ln2_b,
    const float* __restrict__ w1, const float* __restrict__ b1,
    const float* __restrict__ w2, const float* __restrict__ b2,
    float* __restrict__ out)
{
    // per-batch-half regions [2]; weights/consts shared across halves
    __shared__ alignas(16) unsigned short a_bf[2][NTOK][20];   // amplitudes bf16
    __shared__ alignas(16) unsigned short wa_bf[2][NTOK][20];  // log2e*Wa bf16
    __shared__ alignas(16) unsigned short vxT[2][17][268];     // |Wa|^T + ones row
    __shared__ alignas(16) unsigned short w1tb[64][20];        // w1^T bf16 [k][e]
    __shared__ alignas(16) unsigned short w2tb[16][68];        // w2^T bf16 [d][k]
    __shared__ alignas(16) float b1_lds[64];
    __shared__ alignas(16) float ln2g_lds[DD];
    __shared__ alignas(16) float ln2b_lds[DD];
    __shared__ alignas(16) float b2_lds[DD];

    const int tid  = threadIdx.x;
    const int h    = tid >> 9;            // batch half within block
    const int b    = blockIdx.x * 2 + h;  // batch
    const int tl   = tid & 511;           // local tid within half
    const int r    = tl & (NTOK - 1);
    const int q    = tl >> 8;
    const int wl   = tl >> 6;             // wave-in-half 0..7 = i-strip
    const int l31  = tid & 31;
    const int hi   = (tid >> 5) & 1;
    const int lane = tid & 63;

    // issue residual-x loads early (row = my attention lane-row)
    const float* xres = x + ((size_t)b * NTOK + 32 * wl + l31) * DD;
    const float4 xra = *(const float4*)(xres + 4 * hi);
    const float4 xrb = *(const float4*)(xres + 8 + 4 * hi);

    f32x16 zc;
    #pragma unroll
    for (int t = 0; t < 16; ++t) zc[t] = 0.0f;

    // ---------------- P0: LN1 + amp chain (all threads; row r of batch b) -----
    float amp[DD];
    {
        const float* xrow = x + ((size_t)b * NTOK + r) * DD;
        float xr[DD];
        #pragma unroll
        for (int qq = 0; qq < 4; ++qq) {
            float4 v = ((const float4*)xrow)[qq];
            xr[4*qq+0] = v.x; xr[4*qq+1] = v.y; xr[4*qq+2] = v.z; xr[4*qq+3] = v.w;
        }
        float mu = 0.0f;
        #pragma unroll
        for (int d = 0; d < DD; ++d) mu += xr[d];
        mu *= (1.0f / DD);
        float var = 0.0f;
        #pragma unroll
        for (int d = 0; d < DD; ++d) { float dv = xr[d] - mu; var += dv * dv; }
        var *= (1.0f / DD);
        float rs = 1.0f / sqrtf(var + 1e-5f);
        float inp[DD];
        #pragma unroll
        for (int d = 0; d < DD; ++d)
            inp[d] = ((xr[d] - mu) * rs * ln1_g[d] + ln1_b[d]) * 0.5f;

        // Spherical decomposition reconstructs its input; track prefix^2 only.
        float P = 1.0f;
        #pragma unroll
        for (int i = 0; i < DD - 1; ++i) {
            float v = inp[i];
            float v2 = v * v;
            bool ok = v2 <= P;
            amp[i] = ok ? v : __builtin_amdgcn_sqrtf(P);
            P = ok ? __builtin_fmaf(-v, v, P) : 0.0f;
        }
        amp[DD - 1] = __builtin_amdgcn_sqrtf(P);
    }

    if (q == 0) {
        // ---- write a_bf; h==0's q0 also stages shared weights/consts ----
        u32 aw[8];
        #pragma unroll
        for (int k = 0; k < 8; ++k)
            asm("v_cvt_pk_bf16_f32 %0, %1, %2" : "=v"(aw[k]) : "v"(amp[2*k]), "v"(amp[2*k+1]));
        *(u64*)&a_bf[h][r][0]  = (u64)aw[0] | ((u64)aw[1] << 32);
        *(u64*)&a_bf[h][r][4]  = (u64)aw[2] | ((u64)aw[3] << 32);
        *(u64*)&a_bf[h][r][8]  = (u64)aw[4] | ((u64)aw[5] << 32);
        *(u64*)&a_bf[h][r][12] = (u64)aw[6] | ((u64)aw[7] << 32);
        if (h == 0) {
            for (int i = r; i < 64 * DD; i += NTOK) {
                w1tb[i & 63][i >> 6] = (unsigned short)f2bf(w1[i]);   // w1^T
                w2tb[i & 15][i >> 4] = (unsigned short)f2bf(w2[i]);   // w2^T
            }
            if (r >= 128 && r < 192) b1_lds[r - 128] = b1[r - 128];
            if (r >= 192 && r < 208) ln2g_lds[r - 192] = ln2_g[r - 192];
            if (r >= 208 && r < 224) ln2b_lds[r - 208] = ln2_b[r - 208];
            if (r >= 224 && r < 240) b2_lds[r - 224] = b2[r - 224];
        }
        vxT[h][16][r] = 0x3F80;   // ones row -> softmax denominator
    } else {
        // ---- Wa = butterfly rotations applied directly to amp (in place) ----
        float sn_l = 0.0f, cs_l = 0.0f;
        if (lane < 32) __sincosf(angles[lane], &sn_l, &cs_l);
        #pragma unroll
        for (int s = 0; s < 4; ++s) {
            const int step = 1 << s;
            #pragma unroll
            for (int p = 0; p < 8; ++p) {
                const int i = ((p >> s) << (s + 1)) | (p & (step - 1));
                const int j = i + step;
                float sn = __shfl(sn_l, s * 8 + p, 64);   // v_readlane broadcast
                float cs = __shfl(cs_l, s * 8 + p, 64);
                float vi = amp[i], vj = amp[j];
                amp[i] =  cs * vi + sn * vj;
                amp[j] = -sn * vi + cs * vj;
            }
        }
        // wa_bf pre-scaled by log2(e): P2 then uses native exp2f (no mul)
        const float L2E = 1.4426950408889634f;
        u32 ww[8];
        #pragma unroll
        for (int k = 0; k < 8; ++k)
            asm("v_cvt_pk_bf16_f32 %0, %1, %2" : "=v"(ww[k])
                : "v"(amp[2*k] * L2E), "v"(amp[2*k+1] * L2E));
        *(u64*)&wa_bf[h][r][0]  = (u64)ww[0] | ((u64)ww[1] << 32);
        *(u64*)&wa_bf[h][r][4]  = (u64)ww[2] | ((u64)ww[3] << 32);
        *(u64*)&wa_bf[h][r][8]  = (u64)ww[4] | ((u64)ww[5] << 32);
        *(u64*)&wa_bf[h][r][12] = (u64)ww[6] | ((u64)ww[7] << 32);
        #pragma unroll
        for (int d = 0; d < DD; ++d)
            vxT[h][d][r] = (unsigned short)f2bf(fabsf(amp[d]));
    }
    __syncthreads();
    // ======== everything below is barrier-free and per-wave independent ========

    // ---------------- P2: attention. O^T orientation: lane = token, regs = d --
    const int ncl = (l31 < 16) ? l31 : 16;   // vx A-frag row clamp (row16 = ones)
    f32x16 Oacc = zc;
    {
        short8 waf = ld8(&wa_bf[h][32 * wl + l31][8 * hi]);   // B-frag: col i, k = d
        #pragma unroll
        for (int jt = 0; jt < 8; ++jt) {
            short8 af = ld8(&a_bf[h][jt * 32 + l31][8 * hi]); // A-frag: row j, k = d
            // S': lane holds log2e * S[i = 32wl + l31][j = 32jt + pat(t,hi)]
            f32x16 S = __builtin_amdgcn_mfma_f32_32x32x16_bf16(af, waf, zc, 0, 0, 0);
            f32x16 pv;
            #pragma unroll
            for (int t = 0; t < 16; ++t) pv[t] = exp2f(fabsf(S[t]));  // = exp(|S|)
            short8 pb0, pb1;
            pack_swap16(pv, pb0, pb1);                        // B-frags: col i, k = j
            short8 va0 = ld8(&vxT[h][ncl][jt * 32 + 8 * hi]); // A-frags: row d, k = j
            short8 va1 = ld8(&vxT[h][ncl][jt * 32 + 16 + 8 * hi]);
            Oacc = __builtin_amdgcn_mfma_f32_32x32x16_bf16(va0, pb0, Oacc, 0, 0, 0);
            Oacc = __builtin_amdgcn_mfma_f32_32x32x16_bf16(va1, pb1, Oacc, 0, 0, 0);
        }
    }

    // ---------------- P3: residual + LN2, in-register (lane pairs) ------------
    // Oacc[8] = row 16 (hi=0) / 20 (hi=1); rows 16..31 all = l (clamped ones-row)
    const float rl = 1.0f / Oacc[8];
    float o1[8];
    o1[0] = xra.x + Oacc[0] * rl;  o1[1] = xra.y + Oacc[1] * rl;
    o1[2] = xra.z + Oacc[2] * rl;  o1[3] = xra.w + Oacc[3] * rl;
    o1[4] = xrb.x + Oacc[4] * rl;  o1[5] = xrb.y + Oacc[5] * rl;
    o1[6] = xrb.z + Oacc[6] * rl;  o1[7] = xrb.w + Oacc[7] * rl;

    float s8 = 0.0f;
    #pragma unroll
    for (int t = 0; t < 8; ++t) s8 += o1[t];
    float mu2 = (s8 + __shfl_xor(s8, 32, 64)) * (1.0f / DD);
    float v8 = 0.0f;
    #pragma unroll
    for (int t = 0; t < 8; ++t) { float dv = o1[t] - mu2; v8 += dv * dv; }
    float var2 = (v8 + __shfl_xor(v8, 32, 64)) * (1.0f / DD);
    float rs2 = 1.0f / sqrtf(var2 + 1e-5f);

    const float4 g0v = *(const float4*)&ln2g_lds[4 * hi];
    const float4 g1v = *(const float4*)&ln2g_lds[8 + 4 * hi];
    const float4 bb0 = *(const float4*)&ln2b_lds[4 * hi];
    const float4 bb1 = *(const float4*)&ln2b_lds[8 + 4 * hi];
    float hv[8];
    hv[0] = (o1[0]-mu2)*rs2*g0v.x + bb0.x;  hv[1] = (o1[1]-mu2)*rs2*g0v.y + bb0.y;
    hv[2] = (o1[2]-mu2)*rs2*g0v.z + bb0.z;  hv[3] = (o1[3]-mu2)*rs2*g0v.w + bb0.w;
    hv[4] = (o1[4]-mu2)*rs2*g1v.x + bb1.x;  hv[5] = (o1[5]-mu2)*rs2*g1v.y + bb1.y;
    hv[6] = (o1[6]-mu2)*rs2*g1v.z + bb1.z;  hv[7] = (o1[7]-mu2)*rs2*g1v.w + bb1.w;

    short8 hB;   // B-frag (col = token, k = d)
    {
        u32 w0, w1u, w2u, w3;
        asm("v_cvt_pk_bf16_f32 %0, %1, %2" : "=v"(w0)  : "v"(hv[0]), "v"(hv[1]));
        asm("v_cvt_pk_bf16_f32 %0, %1, %2" : "=v"(w1u) : "v"(hv[2]), "v"(hv[3]));
        asm("v_cvt_pk_bf16_f32 %0, %1, %2" : "=v"(w2u) : "v"(hv[4]), "v"(hv[5]));
        asm("v_cvt_pk_bf16_f32 %0, %1, %2" : "=v"(w3)  : "v"(hv[6]), "v"(hv[7]));
        asm("s_nop 1\n\tv_permlane32_swap_b32 %0, %1" : "+v"(w0),  "+v"(w2u));
        asm("s_nop 1\n\tv_permlane32_swap_b32 %0, %1" : "+v"(w1u), "+v"(w3));
        struct { u32 x, y, z, w; } hw{w0, w1u, w2u, w3};
        hB = __builtin_bit_cast(short8, hw);
    }

    // ---------------- P4: MLP via MFMA, lane=token orientation ----------------
    const int dcl = (l31 < 15) ? l31 : 15;   // w2 A-frag row clamp
    f32x16 O2 = zc;
    {
        const float4 c0 = *(const float4*)&b2_lds[4 * hi];
        const float4 c1 = *(const float4*)&b2_lds[8 + 4 * hi];
        O2[0] = c0.x; O2[1] = c0.y; O2[2] = c0.z; O2[3] = c0.w;
        O2[4] = c1.x; O2[5] = c1.y; O2[6] = c1.z; O2[7] = c1.w;
    }
    #pragma unroll
    for (int kblk = 0; kblk < 2; ++kblk) {
        f32x16 Hc;
        {
            const float* bp = &b1_lds[32 * kblk];
            const float4 c0 = *(const float4*)(bp + 4 * hi);
            const float4 c1 = *(const float4*)(bp + 8 + 4 * hi);
            const float4 c2 = *(const float4*)(bp + 16 + 4 * hi);
            const float4 c3 = *(const float4*)(bp + 24 + 4 * hi);
            Hc[0]=c0.x; Hc[1]=c0.y; Hc[2]=c0.z; Hc[3]=c0.w;
            Hc[4]=c1.x; Hc[5]=c1.y; Hc[6]=c1.z; Hc[7]=c1.w;
            Hc[8]=c2.x; Hc[9]=c2.y; Hc[10]=c2.z; Hc[11]=c2.w;
            Hc[12]=c3.x; Hc[13]=c3.y; Hc[14]=c3.z; Hc[15]=c3.w;
        }
        short8 w1f = ld8(&w1tb[32 * kblk + l31][8 * hi]);
        f32x16 H = __builtin_amdgcn_mfma_f32_32x32x16_bf16(w1f, hB, Hc, 0, 0, 0);
        f32x16 gv;
        #pragma unroll
        for (int t = 0; t < 16; ++t) gv[t] = gelu_erf(H[t]);
        short8 gb0, gb1;
        pack_swap16(gv, gb0, gb1);
        short8 w2f0 = ld8(&w2tb[dcl][32 * kblk + 8 * hi]);
        short8 w2f1 = ld8(&w2tb[dcl][32 * kblk + 16 + 8 * hi]);
        O2 = __builtin_amdgcn_mfma_f32_32x32x16_bf16(w2f0, gb0, O2, 0, 0, 0);
        O2 = __builtin_amdgcn_mfma_f32_32x32x16_bf16(w2f1, gb1, O2, 0, 0, 0);
    }

    // ---------------- P5: out = o1 + O2 (+b2 already in O2), direct store -----
    {
        float* orow = out + ((size_t)b * NTOK + 32 * wl + l31) * DD;
        float4 oa, ob;
        oa.x = o1[0] + O2[0]; oa.y = o1[1] + O2[1];
        oa.z = o1[2] + O2[2]; oa.w = o1[3] + O2[3];
        ob.x = o1[4] + O2[4]; ob.y = o1[5] + O2[5];
        ob.z = o1[6] + O2[6]; ob.w = o1[7] + O2[7];
        *(float4*)(orow + 4 * hi) = oa;
        *(float4*)(orow + 8 + 4 * hi) = ob;
    }
}

extern "C" void kernel_launch(void* const* d_in, const int* in_sizes, int n_in,
                              void* d_out, int out_size, void* d_ws, size_t ws_size,
                              hipStream_t stream) {
    const float* x     = (const float*)d_in[0];
    const float* ln1_g = (const float*)d_in[1];
    const float* ln1_b = (const float*)d_in[2];
    const float* ang   = (const float*)d_in[3];
    const float* ln2_g = (const float*)d_in[4];
    const float* ln2_b = (const float*)d_in[5];
    const float* w1    = (const float*)d_in[6];
    const float* b1    = (const float*)d_in[7];
    const float* w2    = (const float*)d_in[8];
    const float* b2    = (const float*)d_in[9];
    float* out = (float*)d_out;

    const int B = in_sizes[0] / (NTOK * DD);
    hipLaunchKernelGGL(qab_kernel, dim3(B / 2), dim3(BDIM), 0, stream,
                       x, ln1_g, ln1_b, ang, ln2_g, ln2_b, w1, b1, w2, b2, out);
}

// Round 14
// 24.225 us; speedup vs baseline: 1.0406x; 1.0033x over previous
//
#include <hip/hip_runtime.h>
#include <math.h>

#define NTOK 256
#define DD 16
#define BDIM 512

typedef short short8 __attribute__((ext_vector_type(8)));
typedef float f32x16 __attribute__((ext_vector_type(16)));
typedef unsigned int u32;
typedef unsigned long long u64;

__device__ __forceinline__ u32 f2bf(float f) {
    u32 u = __float_as_uint(f);
    u += 0x7FFFu + ((u >> 16) & 1u);
    return u >> 16;
}
__device__ __forceinline__ float bf2f(unsigned short h) {
    return __uint_as_float(((u32)h) << 16);
}
struct U128 { u64 a, b; };
__device__ __forceinline__ short8 ld8(const unsigned short* p) {
    U128 t;
    t.a = *(const u64*)(p);
    t.b = *(const u64*)(p + 4);
    return __builtin_bit_cast(short8, t);
}
// pack 16 f32 (reg t -> k-offset pat(t,hi)=(t&3)+8*(t>>2)+4*hi) into two
// fragment short8s with k = 8*hi+e (f0: k 0..15, f1: k 16..31). HW-validated R3/R4/R6.
__device__ __forceinline__ void pack_swap16(f32x16 p, short8& f0, short8& f1) {
    u32 W00, W01, W10, W11, W20, W21, W30, W31;
    asm("v_cvt_pk_bf16_f32 %0, %1, %2" : "=v"(W00) : "v"(p[0]),  "v"(p[1]));
    asm("v_cvt_pk_bf16_f32 %0, %1, %2" : "=v"(W01) : "v"(p[2]),  "v"(p[3]));
    asm("v_cvt_pk_bf16_f32 %0, %1, %2" : "=v"(W10) : "v"(p[4]),  "v"(p[5]));
    asm("v_cvt_pk_bf16_f32 %0, %1, %2" : "=v"(W11) : "v"(p[6]),  "v"(p[7]));
    asm("v_cvt_pk_bf16_f32 %0, %1, %2" : "=v"(W20) : "v"(p[8]),  "v"(p[9]));
    asm("v_cvt_pk_bf16_f32 %0, %1, %2" : "=v"(W21) : "v"(p[10]), "v"(p[11]));
    asm("v_cvt_pk_bf16_f32 %0, %1, %2" : "=v"(W30) : "v"(p[12]), "v"(p[13]));
    asm("v_cvt_pk_bf16_f32 %0, %1, %2" : "=v"(W31) : "v"(p[14]), "v"(p[15]));
    asm("v_permlane32_swap_b32 %0, %1" : "+v"(W00), "+v"(W10));
    asm("v_permlane32_swap_b32 %0, %1" : "+v"(W01), "+v"(W11));
    asm("v_permlane32_swap_b32 %0, %1" : "+v"(W20), "+v"(W30));
    asm("v_permlane32_swap_b32 %0, %1" : "+v"(W21), "+v"(W31));
    struct { u32 x, y, z, w; } i0{W00, W01, W10, W11}, i1{W20, W21, W30, W31};
    f0 = __builtin_bit_cast(short8, i0);
    f1 = __builtin_bit_cast(short8, i1);
}
// exact-GELU via Abramowitz-Stegun 7.1.26 erf (|err| <= 1.5e-7)
__device__ __forceinline__ float gelu_erf(float v) {
    float xx = v * 0.70710678118654752f;
    float ax = fabsf(xx);
    float t = __builtin_amdgcn_rcpf(__builtin_fmaf(0.3275911f, ax, 1.0f));
    float poly = t * (0.254829592f + t * (-0.284496736f + t * (1.421413741f
               + t * (-1.453152027f + t * 1.061405429f))));
    float r = 1.0f - poly * __expf(-ax * ax);
    float e = copysignf(r, xx);
    return 0.5f * v * (1.0f + e);
}

// ========================= kernel A: per-row prep ==========================
// One thread per (batch,row): LN1 + spherical-decomposition amplitudes,
// stored as bf16x16 (32 B/row, coalesced). No LDS, no barriers.
__global__ __launch_bounds__(256, 8) void qab_prep(
    const float* __restrict__ x,
    const float* __restrict__ ln1_g, const float* __restrict__ ln1_b,
    u64* __restrict__ a_g)
{
    const size_t row = (size_t)blockIdx.x * 256 + threadIdx.x;
    const float* xrow = x + row * DD;
    float xr[DD];
    #pragma unroll
    for (int qq = 0; qq < 4; ++qq) {
        float4 v = ((const float4*)xrow)[qq];
        xr[4*qq+0] = v.x; xr[4*qq+1] = v.y; xr[4*qq+2] = v.z; xr[4*qq+3] = v.w;
    }
    float mu = 0.0f;
    #pragma unroll
    for (int d = 0; d < DD; ++d) mu += xr[d];
    mu *= (1.0f / DD);
    float var = 0.0f;
    #pragma unroll
    for (int d = 0; d < DD; ++d) { float dv = xr[d] - mu; var += dv * dv; }
    var *= (1.0f / DD);
    float rs = 1.0f / sqrtf(var + 1e-5f);
    float inp[DD];
    #pragma unroll
    for (int d = 0; d < DD; ++d)
        inp[d] = ((xr[d] - mu) * rs * ln1_g[d] + ln1_b[d]) * 0.5f;

    // Spherical decomposition reconstructs its input; track prefix^2 only.
    float amp[DD];
    float P = 1.0f;
    #pragma unroll
    for (int i = 0; i < DD - 1; ++i) {
        float v = inp[i];
        float v2 = v * v;
        bool ok = v2 <= P;
        amp[i] = ok ? v : __builtin_amdgcn_sqrtf(P);
        P = ok ? __builtin_fmaf(-v, v, P) : 0.0f;
    }
    amp[DD - 1] = __builtin_amdgcn_sqrtf(P);

    u32 aw[8];
    #pragma unroll
    for (int k = 0; k < 8; ++k)
        asm("v_cvt_pk_bf16_f32 %0, %1, %2" : "=v"(aw[k]) : "v"(amp[2*k]), "v"(amp[2*k+1]));
    ulonglong2 v0, v1;
    v0.x = (u64)aw[0] | ((u64)aw[1] << 32);
    v0.y = (u64)aw[2] | ((u64)aw[3] << 32);
    v1.x = (u64)aw[4] | ((u64)aw[5] << 32);
    v1.y = (u64)aw[6] | ((u64)aw[7] << 32);
    u64* dst = a_g + row * 4;
    *(ulonglong2*)(dst)     = v0;
    *(ulonglong2*)(dst + 2) = v1;
}

// ========================= kernel B: attention + MLP =======================
__global__ __launch_bounds__(BDIM, 4) void qab_main(
    const float* __restrict__ x,
    const float* __restrict__ angles,
    const float* __restrict__ ln2_g, const float* __restrict__ ln2_b,
    const float* __restrict__ w1, const float* __restrict__ b1,
    const float* __restrict__ w2, const float* __restrict__ b2,
    const u64* __restrict__ a_g,
    float* __restrict__ out)
{
    __shared__ alignas(16) unsigned short a_bf[NTOK][20];   // amplitudes bf16
    __shared__ alignas(16) unsigned short wa_bf[NTOK][20];  // Wa bf16
    __shared__ alignas(16) unsigned short vxT[17][268];     // |Wa|^T + ones row
    __shared__ alignas(16) unsigned short w1tb[64][20];     // w1^T bf16 [k][e]
    __shared__ alignas(16) unsigned short w2tb[16][68];     // w2^T bf16 [d][k]
    __shared__ alignas(16) float b1_lds[64];
    __shared__ alignas(16) float ln2g_lds[DD];
    __shared__ alignas(16) float ln2b_lds[DD];
    __shared__ alignas(16) float b2_lds[DD];

    const int b    = blockIdx.x;
    const int tid  = threadIdx.x;
    const int r    = tid & (NTOK - 1);
    const int q    = tid >> 8;
    const int w    = tid >> 6;
    const int l31  = tid & 31;
    const int hi   = (tid >> 5) & 1;
    const int lane = tid & 63;

    // issue residual-x loads early (row = my attention lane-row)
    const float* xres = x + ((size_t)b * NTOK + 32 * w + l31) * DD;
    const float4 xra = *(const float4*)(xres + 4 * hi);
    const float4 xrb = *(const float4*)(xres + 8 + 4 * hi);

    f32x16 zc;
    #pragma unroll
    for (int t = 0; t < 16; ++t) zc[t] = 0.0f;

    // ---------------- P0: bulk-load a; q1 applies butterfly -------------------
    const u64* src = a_g + ((size_t)b * NTOK + r) * 4;
    const ulonglong2 t0 = *(const ulonglong2*)(src);
    const ulonglong2 t1 = *(const ulonglong2*)(src + 2);

    if (q == 0) {
        // ---- a straight into LDS + stage weights/consts ----
        *(u64*)&a_bf[r][0]  = t0.x;
        *(u64*)&a_bf[r][4]  = t0.y;
        *(u64*)&a_bf[r][8]  = t1.x;
        *(u64*)&a_bf[r][12] = t1.y;
        for (int i = r; i < 64 * DD; i += NTOK) {
            w1tb[i & 63][i >> 6] = (unsigned short)f2bf(w1[i]);   // w1^T
            w2tb[i & 15][i >> 4] = (unsigned short)f2bf(w2[i]);   // w2^T
        }
        if (r >= 128 && r < 192) b1_lds[r - 128] = b1[r - 128];
        if (r >= 192 && r < 208) ln2g_lds[r - 192] = ln2_g[r - 192];
        if (r >= 208 && r < 224) ln2b_lds[r - 208] = ln2_b[r - 208];
        if (r >= 224 && r < 240) b2_lds[r - 224] = b2[r - 224];
        vxT[16][r] = 0x3F80;   // ones row -> softmax denominator
    } else {
        // ---- unpack a, butterfly rotations in place -> Wa ----
        float amp[DD];
        {
            u64 words[4] = { t0.x, t0.y, t1.x, t1.y };
            #pragma unroll
            for (int j = 0; j < 4; ++j)
                #pragma unroll
                for (int e = 0; e < 4; ++e)
                    amp[4*j + e] = bf2f((unsigned short)(words[j] >> (16 * e)));
        }
        float sn_l = 0.0f, cs_l = 0.0f;
        if (lane < 32) __sincosf(angles[lane], &sn_l, &cs_l);
        #pragma unroll
        for (int s = 0; s < 4; ++s) {
            const int step = 1 << s;
            #pragma unroll
            for (int p = 0; p < 8; ++p) {
                const int i = ((p >> s) << (s + 1)) | (p & (step - 1));
                const int j = i + step;
                float sn = __shfl(sn_l, s * 8 + p, 64);   // v_readlane broadcast
                float cs = __shfl(cs_l, s * 8 + p, 64);
                float vi = amp[i], vj = amp[j];
                amp[i] =  cs * vi + sn * vj;
                amp[j] = -sn * vi + cs * vj;
            }
        }
        u32 ww[8];
        #pragma unroll
        for (int k = 0; k < 8; ++k)
            asm("v_cvt_pk_bf16_f32 %0, %1, %2" : "=v"(ww[k]) : "v"(amp[2*k]), "v"(amp[2*k+1]));
        *(u64*)&wa_bf[r][0]  = (u64)ww[0] | ((u64)ww[1] << 32);
        *(u64*)&wa_bf[r][4]  = (u64)ww[2] | ((u64)ww[3] << 32);
        *(u64*)&wa_bf[r][8]  = (u64)ww[4] | ((u64)ww[5] << 32);
        *(u64*)&wa_bf[r][12] = (u64)ww[6] | ((u64)ww[7] << 32);
        #pragma unroll
        for (int d = 0; d < DD; ++d)
            vxT[d][r] = (unsigned short)f2bf(fabsf(amp[d]));
    }
    __syncthreads();
    // ======== everything below is barrier-free and per-wave independent ========

    // ---------------- P2: attention, 2-deep software pipeline -----------------
    const int ncl = (l31 < 16) ? l31 : 16;   // vx A-frag row clamp (row16 = ones)
    f32x16 Oacc = zc;
    {
        short8 waf = ld8(&wa_bf[w * 32 + l31][8 * hi]);   // B-frag: col i, k = d
        short8 af[8];
        #pragma unroll
        for (int jt = 0; jt < 8; ++jt)
            af[jt] = ld8(&a_bf[jt * 32 + l31][8 * hi]);
        short8 va0 = ld8(&vxT[ncl][8 * hi]);
        short8 va1 = ld8(&vxT[ncl][16 + 8 * hi]);
        f32x16 S0 = __builtin_amdgcn_mfma_f32_32x32x16_bf16(af[0], waf, zc, 0, 0, 0);
        #pragma unroll
        for (int jt = 0; jt < 8; ++jt) {
            f32x16 Sn;
            if (jt < 7)
                Sn = __builtin_amdgcn_mfma_f32_32x32x16_bf16(af[jt + 1], waf, zc, 0, 0, 0);
            short8 nva0, nva1;
            if (jt < 7) {
                nva0 = ld8(&vxT[ncl][(jt + 1) * 32 + 8 * hi]);
                nva1 = ld8(&vxT[ncl][(jt + 1) * 32 + 16 + 8 * hi]);
            }
            f32x16 pv;
            #pragma unroll
            for (int t = 0; t < 16; ++t) pv[t] = __expf(fabsf(S0[t]));  // s in [0,1]
            short8 pb0, pb1;
            pack_swap16(pv, pb0, pb1);                     // B-frags: col i, k = j
            Oacc = __builtin_amdgcn_mfma_f32_32x32x16_bf16(va0, pb0, Oacc, 0, 0, 0);
            Oacc = __builtin_amdgcn_mfma_f32_32x32x16_bf16(va1, pb1, Oacc, 0, 0, 0);
            S0 = Sn; va0 = nva0; va1 = nva1;
        }
    }

    // ---------------- P3: residual + LN2, in-register (lane pairs) ------------
    // Oacc[8] = row 16 (hi=0) / 20 (hi=1); rows 16..31 all = l (clamped ones-row)
    const float rl = 1.0f / Oacc[8];
    float o1[8];
    o1[0] = xra.x + Oacc[0] * rl;  o1[1] = xra.y + Oacc[1] * rl;
    o1[2] = xra.z + Oacc[2] * rl;  o1[3] = xra.w + Oacc[3] * rl;
    o1[4] = xrb.x + Oacc[4] * rl;  o1[5] = xrb.y + Oacc[5] * rl;
    o1[6] = xrb.z + Oacc[6] * rl;  o1[7] = xrb.w + Oacc[7] * rl;

    float s8 = 0.0f;
    #pragma unroll
    for (int t = 0; t < 8; ++t) s8 += o1[t];
    float mu2 = (s8 + __shfl_xor(s8, 32, 64)) * (1.0f / DD);
    float v8 = 0.0f;
    #pragma unroll
    for (int t = 0; t < 8; ++t) { float dv = o1[t] - mu2; v8 += dv * dv; }
    float var2 = (v8 + __shfl_xor(v8, 32, 64)) * (1.0f / DD);
    float rs2 = 1.0f / sqrtf(var2 + 1e-5f);

    const float4 g0v = *(const float4*)&ln2g_lds[4 * hi];
    const float4 g1v = *(const float4*)&ln2g_lds[8 + 4 * hi];
    const float4 bb0 = *(const float4*)&ln2b_lds[4 * hi];
    const float4 bb1 = *(const float4*)&ln2b_lds[8 + 4 * hi];
    float h[8];
    h[0] = (o1[0]-mu2)*rs2*g0v.x + bb0.x;  h[1] = (o1[1]-mu2)*rs2*g0v.y + bb0.y;
    h[2] = (o1[2]-mu2)*rs2*g0v.z + bb0.z;  h[3] = (o1[3]-mu2)*rs2*g0v.w + bb0.w;
    h[4] = (o1[4]-mu2)*rs2*g1v.x + bb1.x;  h[5] = (o1[5]-mu2)*rs2*g1v.y + bb1.y;
    h[6] = (o1[6]-mu2)*rs2*g1v.z + bb1.z;  h[7] = (o1[7]-mu2)*rs2*g1v.w + bb1.w;

    short8 hB;   // B-frag (col = token, k = d)
    {
        u32 w0, w1u, w2u, w3;
        asm("v_cvt_pk_bf16_f32 %0, %1, %2" : "=v"(w0)  : "v"(h[0]), "v"(h[1]));
        asm("v_cvt_pk_bf16_f32 %0, %1, %2" : "=v"(w1u) : "v"(h[2]), "v"(h[3]));
        asm("v_cvt_pk_bf16_f32 %0, %1, %2" : "=v"(w2u) : "v"(h[4]), "v"(h[5]));
        asm("v_cvt_pk_bf16_f32 %0, %1, %2" : "=v"(w3)  : "v"(h[6]), "v"(h[7]));
        asm("s_nop 1\n\tv_permlane32_swap_b32 %0, %1" : "+v"(w0),  "+v"(w2u));
        asm("s_nop 1\n\tv_permlane32_swap_b32 %0, %1" : "+v"(w1u), "+v"(w3));
        struct { u32 x, y, z, w; } hw{w0, w1u, w2u, w3};
        hB = __builtin_bit_cast(short8, hw);
    }

    // ---------------- P4: MLP via MFMA, both H tiles in flight ----------------
    const int dcl = (l31 < 15) ? l31 : 15;   // w2 A-frag row clamp
    f32x16 O2 = zc;
    {
        const float4 c0 = *(const float4*)&b2_lds[4 * hi];
        const float4 c1 = *(const float4*)&b2_lds[8 + 4 * hi];
        O2[0] = c0.x; O2[1] = c0.y; O2[2] = c0.z; O2[3] = c0.w;
        O2[4] = c1.x; O2[5] = c1.y; O2[6] = c1.z; O2[7] = c1.w;
    }
    {
        f32x16 Hc0, Hc1;
        #pragma unroll
        for (int kblk = 0; kblk < 2; ++kblk) {
            const float* bp = &b1_lds[32 * kblk];
            const float4 c0 = *(const float4*)(bp + 4 * hi);
            const float4 c1 = *(const float4*)(bp + 8 + 4 * hi);
            const float4 c2 = *(const float4*)(bp + 16 + 4 * hi);
            const float4 c3 = *(const float4*)(bp + 24 + 4 * hi);
            f32x16& Hc = kblk ? Hc1 : Hc0;
            Hc[0]=c0.x; Hc[1]=c0.y; Hc[2]=c0.z; Hc[3]=c0.w;
            Hc[4]=c1.x; Hc[5]=c1.y; Hc[6]=c1.z; Hc[7]=c1.w;
            Hc[8]=c2.x; Hc[9]=c2.y; Hc[10]=c2.z; Hc[11]=c2.w;
            Hc[12]=c3.x; Hc[13]=c3.y; Hc[14]=c3.z; Hc[15]=c3.w;
        }
        short8 w1f0 = ld8(&w1tb[l31][8 * hi]);
        short8 w1f1 = ld8(&w1tb[32 + l31][8 * hi]);
        short8 w2a0 = ld8(&w2tb[dcl][8 * hi]);
        short8 w2a1 = ld8(&w2tb[dcl][16 + 8 * hi]);
        short8 w2b0 = ld8(&w2tb[dcl][32 + 8 * hi]);
        short8 w2b1 = ld8(&w2tb[dcl][48 + 8 * hi]);
        f32x16 H0 = __builtin_amdgcn_mfma_f32_32x32x16_bf16(w1f0, hB, Hc0, 0, 0, 0);
        f32x16 H1 = __builtin_amdgcn_mfma_f32_32x32x16_bf16(w1f1, hB, Hc1, 0, 0, 0);
        f32x16 gv0, gv1;
        #pragma unroll
        for (int t = 0; t < 16; ++t) gv0[t] = gelu_erf(H0[t]);
        short8 ga0, ga1;
        pack_swap16(gv0, ga0, ga1);
        #pragma unroll
        for (int t = 0; t < 16; ++t) gv1[t] = gelu_erf(H1[t]);
        short8 gb0, gb1;
        pack_swap16(gv1, gb0, gb1);
        O2 = __builtin_amdgcn_mfma_f32_32x32x16_bf16(w2a0, ga0, O2, 0, 0, 0);
        O2 = __builtin_amdgcn_mfma_f32_32x32x16_bf16(w2a1, ga1, O2, 0, 0, 0);
        O2 = __builtin_amdgcn_mfma_f32_32x32x16_bf16(w2b0, gb0, O2, 0, 0, 0);
        O2 = __builtin_amdgcn_mfma_f32_32x32x16_bf16(w2b1, gb1, O2, 0, 0, 0);
    }

    // ---------------- P5: out = o1 + O2 (+b2 already in O2), direct store -----
    {
        float* orow = out + ((size_t)b * NTOK + 32 * w + l31) * DD;
        float4 oa, ob;
        oa.x = o1[0] + O2[0]; oa.y = o1[1] + O2[1];
        oa.z = o1[2] + O2[2]; oa.w = o1[3] + O2[3];
        ob.x = o1[4] + O2[4]; ob.y = o1[5] + O2[5];
        ob.z = o1[6] + O2[6]; ob.w = o1[7] + O2[7];
        *(float4*)(orow + 4 * hi) = oa;
        *(float4*)(orow + 8 + 4 * hi) = ob;
    }
}

extern "C" void kernel_launch(void* const* d_in, const int* in_sizes, int n_in,
                              void* d_out, int out_size, void* d_ws, size_t ws_size,
                              hipStream_t stream) {
    const float* x     = (const float*)d_in[0];
    const float* ln1_g = (const float*)d_in[1];
    const float* ln1_b = (const float*)d_in[2];
    const float* ang   = (const float*)d_in[3];
    const float* ln2_g = (const float*)d_in[4];
    const float* ln2_b = (const float*)d_in[5];
    const float* w1    = (const float*)d_in[6];
    const float* b1    = (const float*)d_in[7];
    const float* w2    = (const float*)d_in[8];
    const float* b2    = (const float*)d_in[9];
    float* out = (float*)d_out;

    const int B = in_sizes[0] / (NTOK * DD);
    u64* a_g = (u64*)d_ws;   // B*256 rows x 32 B = 4.2 MB for B=512

    hipLaunchKernelGGL(qab_prep, dim3(B), dim3(256), 0, stream,
                       x, ln1_g, ln1_b, a_g);
    hipLaunchKernelGGL(qab_main, dim3(B), dim3(BDIM), 0, stream,
                       x, ang, ln2_g, ln2_b, w1, b1, w2, b2, a_g, out);
}

// Round 15
// 23.944 us; speedup vs baseline: 1.0529x; 1.0118x over previous
//
#include <hip/hip_runtime.h>
#include <math.h>

#define NTOK 256
#define DD 16
#define BDIM 512

typedef short short8 __attribute__((ext_vector_type(8)));
typedef float f32x16 __attribute__((ext_vector_type(16)));
typedef unsigned int u32;
typedef unsigned long long u64;

__device__ __forceinline__ u32 f2bf(float f) {
    u32 u = __float_as_uint(f);
    u += 0x7FFFu + ((u >> 16) & 1u);
    return u >> 16;
}
struct U128 { u64 a, b; };
__device__ __forceinline__ short8 ld8(const unsigned short* p) {
    U128 t;
    t.a = *(const u64*)(p);
    t.b = *(const u64*)(p + 4);
    return __builtin_bit_cast(short8, t);
}
// pack 16 f32 (reg t -> k-offset pat(t,hi)=(t&3)+8*(t>>2)+4*hi) into two
// fragment short8s with k = 8*hi+e (f0: k 0..15, f1: k 16..31). HW-validated R3/R4/R6.
__device__ __forceinline__ void pack_swap16(f32x16 p, short8& f0, short8& f1) {
    u32 W00, W01, W10, W11, W20, W21, W30, W31;
    asm("v_cvt_pk_bf16_f32 %0, %1, %2" : "=v"(W00) : "v"(p[0]),  "v"(p[1]));
    asm("v_cvt_pk_bf16_f32 %0, %1, %2" : "=v"(W01) : "v"(p[2]),  "v"(p[3]));
    asm("v_cvt_pk_bf16_f32 %0, %1, %2" : "=v"(W10) : "v"(p[4]),  "v"(p[5]));
    asm("v_cvt_pk_bf16_f32 %0, %1, %2" : "=v"(W11) : "v"(p[6]),  "v"(p[7]));
    asm("v_cvt_pk_bf16_f32 %0, %1, %2" : "=v"(W20) : "v"(p[8]),  "v"(p[9]));
    asm("v_cvt_pk_bf16_f32 %0, %1, %2" : "=v"(W21) : "v"(p[10]), "v"(p[11]));
    asm("v_cvt_pk_bf16_f32 %0, %1, %2" : "=v"(W30) : "v"(p[12]), "v"(p[13]));
    asm("v_cvt_pk_bf16_f32 %0, %1, %2" : "=v"(W31) : "v"(p[14]), "v"(p[15]));
    asm("v_permlane32_swap_b32 %0, %1" : "+v"(W00), "+v"(W10));
    asm("v_permlane32_swap_b32 %0, %1" : "+v"(W01), "+v"(W11));
    asm("v_permlane32_swap_b32 %0, %1" : "+v"(W20), "+v"(W30));
    asm("v_permlane32_swap_b32 %0, %1" : "+v"(W21), "+v"(W31));
    struct { u32 x, y, z, w; } i0{W00, W01, W10, W11}, i1{W20, W21, W30, W31};
    f0 = __builtin_bit_cast(short8, i0);
    f1 = __builtin_bit_cast(short8, i1);
}
// exact-GELU via Abramowitz-Stegun 7.1.26 erf (|err| <= 1.5e-7)
__device__ __forceinline__ float gelu_erf(float v) {
    float xx = v * 0.70710678118654752f;
    float ax = fabsf(xx);
    float t = __builtin_amdgcn_rcpf(__builtin_fmaf(0.3275911f, ax, 1.0f));
    float poly = t * (0.254829592f + t * (-0.284496736f + t * (1.421413741f
               + t * (-1.453152027f + t * 1.061405429f))));
    float r = 1.0f - poly * __expf(-ax * ax);
    float e = copysignf(r, xx);
    return 0.5f * v * (1.0f + e);
}

__global__ __launch_bounds__(BDIM, 4) void qab_kernel(
    const float* __restrict__ x,
    const float* __restrict__ ln1_g, const float* __restrict__ ln1_b,
    const float* __restrict__ angles,
    const float* __restrict__ ln2_g, const float* __restrict__ ln2_b,
    const float* __restrict__ w1, const float* __restrict__ b1,
    const float* __restrict__ w2, const float* __restrict__ b2,
    float* __restrict__ out)
{
    __shared__ alignas(16) unsigned short a_bf[NTOK][20];   // amplitudes bf16
    __shared__ alignas(16) unsigned short wa_bf[NTOK][20];  // log2e * Wa bf16
    __shared__ alignas(16) unsigned short vxT[17][268];     // |Wa|^T + ones row
    __shared__ alignas(16) unsigned short w1tb[64][20];     // w1^T bf16 [k][e]
    __shared__ alignas(16) unsigned short w2tb[16][68];     // w2^T bf16 [d][k]
    __shared__ alignas(16) float b1_lds[64];
    __shared__ alignas(16) float ln2g_lds[DD];
    __shared__ alignas(16) float ln2b_lds[DD];
    __shared__ alignas(16) float b2_lds[DD];

    const int b    = blockIdx.x;
    const int tid  = threadIdx.x;
    const int r    = tid & (NTOK - 1);
    const int q    = tid >> 8;
    const int w    = tid >> 6;
    const int l31  = tid & 31;
    const int hi   = (tid >> 5) & 1;
    const int lane = tid & 63;

    // issue residual-x loads early (row = my attention lane-row)
    const float* xres = x + ((size_t)b * NTOK + 32 * w + l31) * DD;
    const float4 xra = *(const float4*)(xres + 4 * hi);
    const float4 xrb = *(const float4*)(xres + 8 + 4 * hi);

    f32x16 zc;
    #pragma unroll
    for (int t = 0; t < 16; ++t) zc[t] = 0.0f;

    // ---------------- P0: LN1 + amp chain (ALL threads; row r redundant x2) ---
    // q0 issues its w1/w2 staging loads FIRST so HBM latency hides under the
    // amp chain (R15 change b).
    float w1v[4], w2v[4];
    if (q == 0) {
        #pragma unroll
        for (int ii = 0; ii < 4; ++ii) {
            w1v[ii] = w1[r + 256 * ii];
            w2v[ii] = w2[r + 256 * ii];
        }
    }

    float amp[DD];
    {
        const float* xrow = x + ((size_t)b * NTOK + r) * DD;
        float xr[DD];
        #pragma unroll
        for (int qq = 0; qq < 4; ++qq) {
            float4 v = ((const float4*)xrow)[qq];
            xr[4*qq+0] = v.x; xr[4*qq+1] = v.y; xr[4*qq+2] = v.z; xr[4*qq+3] = v.w;
        }
        float mu = 0.0f;
        #pragma unroll
        for (int d = 0; d < DD; ++d) mu += xr[d];
        mu *= (1.0f / DD);
        float var = 0.0f;
        #pragma unroll
        for (int d = 0; d < DD; ++d) { float dv = xr[d] - mu; var += dv * dv; }
        var *= (1.0f / DD);
        float rs = 1.0f / sqrtf(var + 1e-5f);
        float inp[DD];
        #pragma unroll
        for (int d = 0; d < DD; ++d)
            inp[d] = ((xr[d] - mu) * rs * ln1_g[d] + ln1_b[d]) * 0.5f;

        // Spherical decomposition reconstructs its input; track prefix^2 only.
        float P = 1.0f;
        #pragma unroll
        for (int i = 0; i < DD - 1; ++i) {
            float v = inp[i];
            float v2 = v * v;
            bool ok = v2 <= P;
            amp[i] = ok ? v : __builtin_amdgcn_sqrtf(P);
            P = ok ? __builtin_fmaf(-v, v, P) : 0.0f;
        }
        amp[DD - 1] = __builtin_amdgcn_sqrtf(P);
    }

    if (q == 0) {
        // ---- write a_bf + stage weights/consts (loads already in flight) ----
        u32 aw[8];
        #pragma unroll
        for (int k = 0; k < 8; ++k)
            asm("v_cvt_pk_bf16_f32 %0, %1, %2" : "=v"(aw[k]) : "v"(amp[2*k]), "v"(amp[2*k+1]));
        *(u64*)&a_bf[r][0]  = (u64)aw[0] | ((u64)aw[1] << 32);
        *(u64*)&a_bf[r][4]  = (u64)aw[2] | ((u64)aw[3] << 32);
        *(u64*)&a_bf[r][8]  = (u64)aw[4] | ((u64)aw[5] << 32);
        *(u64*)&a_bf[r][12] = (u64)aw[6] | ((u64)aw[7] << 32);
        #pragma unroll
        for (int ii = 0; ii < 4; ++ii) {
            const int i = r + 256 * ii;
            w1tb[i & 63][i >> 6] = (unsigned short)f2bf(w1v[ii]);   // w1^T
            w2tb[i & 15][i >> 4] = (unsigned short)f2bf(w2v[ii]);   // w2^T
        }
        if (r >= 128 && r < 192) b1_lds[r - 128] = b1[r - 128];
        if (r >= 192 && r < 208) ln2g_lds[r - 192] = ln2_g[r - 192];
        if (r >= 208 && r < 224) ln2b_lds[r - 208] = ln2_b[r - 208];
        if (r >= 224 && r < 240) b2_lds[r - 224] = b2[r - 224];
        vxT[16][r] = 0x3F80;   // ones row -> softmax denominator
    } else {
        // ---- Wa = butterfly rotations applied directly to amp (in place) ----
        float sn_l = 0.0f, cs_l = 0.0f;
        if (lane < 32) __sincosf(angles[lane], &sn_l, &cs_l);
        #pragma unroll
        for (int s = 0; s < 4; ++s) {
            const int step = 1 << s;
            #pragma unroll
            for (int p = 0; p < 8; ++p) {
                const int i = ((p >> s) << (s + 1)) | (p & (step - 1));
                const int j = i + step;
                float sn = __shfl(sn_l, s * 8 + p, 64);   // v_readlane broadcast
                float cs = __shfl(cs_l, s * 8 + p, 64);
                float vi = amp[i], vj = amp[j];
                amp[i] =  cs * vi + sn * vj;
                amp[j] = -sn * vi + cs * vj;
            }
        }
        // wa_bf pre-scaled by log2(e): P2's exp(|S|) becomes native exp2f
        const float L2E = 1.4426950408889634f;
        u32 ww[8];
        #pragma unroll
        for (int k = 0; k < 8; ++k)
            asm("v_cvt_pk_bf16_f32 %0, %1, %2" : "=v"(ww[k])
                : "v"(amp[2*k] * L2E), "v"(amp[2*k+1] * L2E));
        *(u64*)&wa_bf[r][0]  = (u64)ww[0] | ((u64)ww[1] << 32);
        *(u64*)&wa_bf[r][4]  = (u64)ww[2] | ((u64)ww[3] << 32);
        *(u64*)&wa_bf[r][8]  = (u64)ww[4] | ((u64)ww[5] << 32);
        *(u64*)&wa_bf[r][12] = (u64)ww[6] | ((u64)ww[7] << 32);
        #pragma unroll
        for (int d = 0; d < DD; ++d)
            vxT[d][r] = (unsigned short)f2bf(fabsf(amp[d]));
    }
    __syncthreads();
    // ======== everything below is barrier-free and per-wave independent ========

    // ---------------- P2: attention, 2-deep software pipeline -----------------
    const int ncl = (l31 < 16) ? l31 : 16;   // vx A-frag row clamp (row16 = ones)
    f32x16 Oacc = zc;
    {
        short8 waf = ld8(&wa_bf[w * 32 + l31][8 * hi]);   // B-frag: col i, k = d
        // preload ALL af A-frags (takes ds_read latency off the chain)
        short8 af[8];
        #pragma unroll
        for (int jt = 0; jt < 8; ++jt)
            af[jt] = ld8(&a_bf[jt * 32 + l31][8 * hi]);
        short8 va0 = ld8(&vxT[ncl][8 * hi]);
        short8 va1 = ld8(&vxT[ncl][16 + 8 * hi]);
        // S pipeline: S for jt+1 issues before pv-processing of jt
        f32x16 S0 = __builtin_amdgcn_mfma_f32_32x32x16_bf16(af[0], waf, zc, 0, 0, 0);
        #pragma unroll
        for (int jt = 0; jt < 8; ++jt) {
            f32x16 Sn;
            if (jt < 7)
                Sn = __builtin_amdgcn_mfma_f32_32x32x16_bf16(af[jt + 1], waf, zc, 0, 0, 0);
            short8 nva0, nva1;
            if (jt < 7) {
                nva0 = ld8(&vxT[ncl][(jt + 1) * 32 + 8 * hi]);
                nva1 = ld8(&vxT[ncl][(jt + 1) * 32 + 16 + 8 * hi]);
            }
            f32x16 pv;
            #pragma unroll
            for (int t = 0; t < 16; ++t) pv[t] = exp2f(fabsf(S0[t]));  // = exp(|S|)
            short8 pb0, pb1;
            pack_swap16(pv, pb0, pb1);                     // B-frags: col i, k = j
            Oacc = __builtin_amdgcn_mfma_f32_32x32x16_bf16(va0, pb0, Oacc, 0, 0, 0);
            Oacc = __builtin_amdgcn_mfma_f32_32x32x16_bf16(va1, pb1, Oacc, 0, 0, 0);
            S0 = Sn; va0 = nva0; va1 = nva1;
        }
    }

    // ---------------- P3: residual + LN2, in-register (lane pairs) ------------
    // Oacc[8] = row 16 (hi=0) / 20 (hi=1); rows 16..31 all = l (clamped ones-row)
    const float rl = 1.0f / Oacc[8];
    float o1[8];
    o1[0] = xra.x + Oacc[0] * rl;  o1[1] = xra.y + Oacc[1] * rl;
    o1[2] = xra.z + Oacc[2] * rl;  o1[3] = xra.w + Oacc[3] * rl;
    o1[4] = xrb.x + Oacc[4] * rl;  o1[5] = xrb.y + Oacc[5] * rl;
    o1[6] = xrb.z + Oacc[6] * rl;  o1[7] = xrb.w + Oacc[7] * rl;

    float s8 = 0.0f;
    #pragma unroll
    for (int t = 0; t < 8; ++t) s8 += o1[t];
    float mu2 = (s8 + __shfl_xor(s8, 32, 64)) * (1.0f / DD);
    float v8 = 0.0f;
    #pragma unroll
    for (int t = 0; t < 8; ++t) { float dv = o1[t] - mu2; v8 += dv * dv; }
    float var2 = (v8 + __shfl_xor(v8, 32, 64)) * (1.0f / DD);
    float rs2 = 1.0f / sqrtf(var2 + 1e-5f);

    const float4 g0v = *(const float4*)&ln2g_lds[4 * hi];
    const float4 g1v = *(const float4*)&ln2g_lds[8 + 4 * hi];
    const float4 bb0 = *(const float4*)&ln2b_lds[4 * hi];
    const float4 bb1 = *(const float4*)&ln2b_lds[8 + 4 * hi];
    float h[8];
    h[0] = (o1[0]-mu2)*rs2*g0v.x + bb0.x;  h[1] = (o1[1]-mu2)*rs2*g0v.y + bb0.y;
    h[2] = (o1[2]-mu2)*rs2*g0v.z + bb0.z;  h[3] = (o1[3]-mu2)*rs2*g0v.w + bb0.w;
    h[4] = (o1[4]-mu2)*rs2*g1v.x + bb1.x;  h[5] = (o1[5]-mu2)*rs2*g1v.y + bb1.y;
    h[6] = (o1[6]-mu2)*rs2*g1v.z + bb1.z;  h[7] = (o1[7]-mu2)*rs2*g1v.w + bb1.w;

    short8 hB;   // B-frag (col = token, k = d)
    {
        u32 w0, w1u, w2u, w3;
        asm("v_cvt_pk_bf16_f32 %0, %1, %2" : "=v"(w0)  : "v"(h[0]), "v"(h[1]));
        asm("v_cvt_pk_bf16_f32 %0, %1, %2" : "=v"(w1u) : "v"(h[2]), "v"(h[3]));
        asm("v_cvt_pk_bf16_f32 %0, %1, %2" : "=v"(w2u) : "v"(h[4]), "v"(h[5]));
        asm("v_cvt_pk_bf16_f32 %0, %1, %2" : "=v"(w3)  : "v"(h[6]), "v"(h[7]));
        asm("s_nop 1\n\tv_permlane32_swap_b32 %0, %1" : "+v"(w0),  "+v"(w2u));
        asm("s_nop 1\n\tv_permlane32_swap_b32 %0, %1" : "+v"(w1u), "+v"(w3));
        struct { u32 x, y, z, w; } hw{w0, w1u, w2u, w3};
        hB = __builtin_bit_cast(short8, hw);
    }

    // ---------------- P4: MLP via MFMA, both H tiles in flight ----------------
    const int dcl = (l31 < 15) ? l31 : 15;   // w2 A-frag row clamp
    f32x16 O2 = zc;
    {
        const float4 c0 = *(const float4*)&b2_lds[4 * hi];
        const float4 c1 = *(const float4*)&b2_lds[8 + 4 * hi];
        O2[0] = c0.x; O2[1] = c0.y; O2[2] = c0.z; O2[3] = c0.w;
        O2[4] = c1.x; O2[5] = c1.y; O2[6] = c1.z; O2[7] = c1.w;
    }
    {
        f32x16 Hc0, Hc1;
        #pragma unroll
        for (int kblk = 0; kblk < 2; ++kblk) {
            const float* bp = &b1_lds[32 * kblk];
            const float4 c0 = *(const float4*)(bp + 4 * hi);
            const float4 c1 = *(const float4*)(bp + 8 + 4 * hi);
            const float4 c2 = *(const float4*)(bp + 16 + 4 * hi);
            const float4 c3 = *(const float4*)(bp + 24 + 4 * hi);
            f32x16& Hc = kblk ? Hc1 : Hc0;
            Hc[0]=c0.x; Hc[1]=c0.y; Hc[2]=c0.z; Hc[3]=c0.w;
            Hc[4]=c1.x; Hc[5]=c1.y; Hc[6]=c1.z; Hc[7]=c1.w;
            Hc[8]=c2.x; Hc[9]=c2.y; Hc[10]=c2.z; Hc[11]=c2.w;
            Hc[12]=c3.x; Hc[13]=c3.y; Hc[14]=c3.z; Hc[15]=c3.w;
        }
        short8 w1f0 = ld8(&w1tb[l31][8 * hi]);
        short8 w1f1 = ld8(&w1tb[32 + l31][8 * hi]);
        short8 w2a0 = ld8(&w2tb[dcl][8 * hi]);
        short8 w2a1 = ld8(&w2tb[dcl][16 + 8 * hi]);
        short8 w2b0 = ld8(&w2tb[dcl][32 + 8 * hi]);
        short8 w2b1 = ld8(&w2tb[dcl][48 + 8 * hi]);
        // both H tiles issue back-to-back; gelu/pack overlap their latency
        f32x16 H0 = __builtin_amdgcn_mfma_f32_32x32x16_bf16(w1f0, hB, Hc0, 0, 0, 0);
        f32x16 H1 = __builtin_amdgcn_mfma_f32_32x32x16_bf16(w1f1, hB, Hc1, 0, 0, 0);
        f32x16 gv0, gv1;
        #pragma unroll
        for (int t = 0; t < 16; ++t) gv0[t] = gelu_erf(H0[t]);
        short8 ga0, ga1;
        pack_swap16(gv0, ga0, ga1);
        #pragma unroll
        for (int t = 0; t < 16; ++t) gv1[t] = gelu_erf(H1[t]);
        short8 gb0, gb1;
        pack_swap16(gv1, gb0, gb1);
        O2 = __builtin_amdgcn_mfma_f32_32x32x16_bf16(w2a0, ga0, O2, 0, 0, 0);
        O2 = __builtin_amdgcn_mfma_f32_32x32x16_bf16(w2a1, ga1, O2, 0, 0, 0);
        O2 = __builtin_amdgcn_mfma_f32_32x32x16_bf16(w2b0, gb0, O2, 0, 0, 0);
        O2 = __builtin_amdgcn_mfma_f32_32x32x16_bf16(w2b1, gb1, O2, 0, 0, 0);
    }

    // ---------------- P5: out = o1 + O2 (+b2 already in O2), direct store -----
    {
        float* orow = out + ((size_t)b * NTOK + 32 * w + l31) * DD;
        float4 oa, ob;
        oa.x = o1[0] + O2[0]; oa.y = o1[1] + O2[1];
        oa.z = o1[2] + O2[2]; oa.w = o1[3] + O2[3];
        ob.x = o1[4] + O2[4]; ob.y = o1[5] + O2[5];
        ob.z = o1[6] + O2[6]; ob.w = o1[7] + O2[7];
        *(float4*)(orow + 4 * hi) = oa;
        *(float4*)(orow + 8 + 4 * hi) = ob;
    }
}

extern "C" void kernel_launch(void* const* d_in, const int* in_sizes, int n_in,
                              void* d_out, int out_size, void* d_ws, size_t ws_size,
                              hipStream_t stream) {
    const float* x     = (const float*)d_in[0];
    const float* ln1_g = (const float*)d_in[1];
    const float* ln1_b = (const float*)d_in[2];
    const float* ang   = (const float*)d_in[3];
    const float* ln2_g = (const float*)d_in[4];
    const float* ln2_b = (const float*)d_in[5];
    const float* w1    = (const float*)d_in[6];
    const float* b1    = (const float*)d_in[7];
    const float* w2    = (const float*)d_in[8];
    const float* b2    = (const float*)d_in[9];
    float* out = (float*)d_out;

    const int B = in_sizes[0] / (NTOK * DD);
    hipLaunchKernelGGL(qab_kernel, dim3(B), dim3(BDIM), 0, stream,
                       x, ln1_g, ln1_b, ang, ln2_g, ln2_b, w1, b1, w2, b2, out);
}

// Round 16
// 19.574 us; speedup vs baseline: 1.2879x; 1.2233x over previous
//
#include <hip/hip_runtime.h>
#include <math.h>

#define NTOK 256
#define DD 16
#define BDIM 512

typedef short short8 __attribute__((ext_vector_type(8)));
typedef float f32x16 __attribute__((ext_vector_type(16)));
typedef unsigned int u32;
typedef unsigned long long u64;

__device__ __forceinline__ u32 f2bf(float f) {
    u32 u = __float_as_uint(f);
    u += 0x7FFFu + ((u >> 16) & 1u);
    return u >> 16;
}
struct U128 { u64 a, b; };
__device__ __forceinline__ short8 ld8(const unsigned short* p) {
    U128 t;
    t.a = *(const u64*)(p);
    t.b = *(const u64*)(p + 4);
    return __builtin_bit_cast(short8, t);
}
// pack 16 f32 (reg t -> k-offset pat(t,hi)=(t&3)+8*(t>>2)+4*hi) into two
// fragment short8s with k = 8*hi+e (f0: k 0..15, f1: k 16..31). HW-validated R3/R4/R6.
__device__ __forceinline__ void pack_swap16(f32x16 p, short8& f0, short8& f1) {
    u32 W00, W01, W10, W11, W20, W21, W30, W31;
    asm("v_cvt_pk_bf16_f32 %0, %1, %2" : "=v"(W00) : "v"(p[0]),  "v"(p[1]));
    asm("v_cvt_pk_bf16_f32 %0, %1, %2" : "=v"(W01) : "v"(p[2]),  "v"(p[3]));
    asm("v_cvt_pk_bf16_f32 %0, %1, %2" : "=v"(W10) : "v"(p[4]),  "v"(p[5]));
    asm("v_cvt_pk_bf16_f32 %0, %1, %2" : "=v"(W11) : "v"(p[6]),  "v"(p[7]));
    asm("v_cvt_pk_bf16_f32 %0, %1, %2" : "=v"(W20) : "v"(p[8]),  "v"(p[9]));
    asm("v_cvt_pk_bf16_f32 %0, %1, %2" : "=v"(W21) : "v"(p[10]), "v"(p[11]));
    asm("v_cvt_pk_bf16_f32 %0, %1, %2" : "=v"(W30) : "v"(p[12]), "v"(p[13]));
    asm("v_cvt_pk_bf16_f32 %0, %1, %2" : "=v"(W31) : "v"(p[14]), "v"(p[15]));
    asm("v_permlane32_swap_b32 %0, %1" : "+v"(W00), "+v"(W10));
    asm("v_permlane32_swap_b32 %0, %1" : "+v"(W01), "+v"(W11));
    asm("v_permlane32_swap_b32 %0, %1" : "+v"(W20), "+v"(W30));
    asm("v_permlane32_swap_b32 %0, %1" : "+v"(W21), "+v"(W31));
    struct { u32 x, y, z, w; } i0{W00, W01, W10, W11}, i1{W20, W21, W30, W31};
    f0 = __builtin_bit_cast(short8, i0);
    f1 = __builtin_bit_cast(short8, i1);
}
// exact-GELU via Abramowitz-Stegun 7.1.26 erf (|err| <= 1.5e-7)
__device__ __forceinline__ float gelu_erf(float v) {
    float xx = v * 0.70710678118654752f;
    float ax = fabsf(xx);
    float t = __builtin_amdgcn_rcpf(__builtin_fmaf(0.3275911f, ax, 1.0f));
    float poly = t * (0.254829592f + t * (-0.284496736f + t * (1.421413741f
               + t * (-1.453152027f + t * 1.061405429f))));
    float r = 1.0f - poly * __expf(-ax * ax);
    float e = copysignf(r, xx);
    return 0.5f * v * (1.0f + e);
}

__global__ __launch_bounds__(BDIM, 4) void qab_kernel(
    const float* __restrict__ x,
    const float* __restrict__ ln1_g, const float* __restrict__ ln1_b,
    const float* __restrict__ angles,
    const float* __restrict__ ln2_g, const float* __restrict__ ln2_b,
    const float* __restrict__ w1, const float* __restrict__ b1,
    const float* __restrict__ w2, const float* __restrict__ b2,
    float* __restrict__ out)
{
    __shared__ alignas(16) unsigned short a_bf[NTOK][20];   // amplitudes bf16
    __shared__ alignas(16) unsigned short wa_bf[NTOK][20];  // log2e * Wa bf16
    __shared__ alignas(16) unsigned short vxT[17][268];     // |Wa|^T + ones row
    __shared__ alignas(16) unsigned short w1tb[64][20];     // w1^T bf16 [k][e]
    __shared__ alignas(16) unsigned short w2tb[16][68];     // w2^T bf16 [d][k]
    __shared__ alignas(16) float b1_lds[64];
    __shared__ alignas(16) float ln2g_lds[DD];
    __shared__ alignas(16) float ln2b_lds[DD];
    __shared__ alignas(16) float b2_lds[DD];

    const int b    = blockIdx.x;
    const int tid  = threadIdx.x;
    const int r    = tid & (NTOK - 1);
    const int q    = tid >> 8;
    const int w    = tid >> 6;
    const int l31  = tid & 31;
    const int hi   = (tid >> 5) & 1;
    const int lane = tid & 63;

    // issue residual-x loads early (row = my attention lane-row)
    const float* xres = x + ((size_t)b * NTOK + 32 * w + l31) * DD;
    const float4 xra = *(const float4*)(xres + 4 * hi);
    const float4 xrb = *(const float4*)(xres + 8 + 4 * hi);

    f32x16 zc;
    #pragma unroll
    for (int t = 0; t < 16; ++t) zc[t] = 0.0f;

    // ---------------- P0: LN1 + amp chain (ALL threads; row r redundant x2) ---
    float amp[DD];
    {
        const float* xrow = x + ((size_t)b * NTOK + r) * DD;
        float xr[DD];
        #pragma unroll
        for (int qq = 0; qq < 4; ++qq) {
            float4 v = ((const float4*)xrow)[qq];
            xr[4*qq+0] = v.x; xr[4*qq+1] = v.y; xr[4*qq+2] = v.z; xr[4*qq+3] = v.w;
        }
        float mu = 0.0f;
        #pragma unroll
        for (int d = 0; d < DD; ++d) mu += xr[d];
        mu *= (1.0f / DD);
        float var = 0.0f;
        #pragma unroll
        for (int d = 0; d < DD; ++d) { float dv = xr[d] - mu; var += dv * dv; }
        var *= (1.0f / DD);
        float rs = 1.0f / sqrtf(var + 1e-5f);
        float inp[DD];
        #pragma unroll
        for (int d = 0; d < DD; ++d)
            inp[d] = ((xr[d] - mu) * rs * ln1_g[d] + ln1_b[d]) * 0.5f;

        // Spherical decomposition reconstructs its input; track prefix^2 only.
        float P = 1.0f;
        #pragma unroll
        for (int i = 0; i < DD - 1; ++i) {
            float v = inp[i];
            float v2 = v * v;
            bool ok = v2 <= P;
            amp[i] = ok ? v : __builtin_amdgcn_sqrtf(P);
            P = ok ? __builtin_fmaf(-v, v, P) : 0.0f;
        }
        amp[DD - 1] = __builtin_amdgcn_sqrtf(P);
    }

    if (q == 0) {
        // ---- write a_bf + stage weights/consts ----
        u32 aw[8];
        #pragma unroll
        for (int k = 0; k < 8; ++k)
            asm("v_cvt_pk_bf16_f32 %0, %1, %2" : "=v"(aw[k]) : "v"(amp[2*k]), "v"(amp[2*k+1]));
        *(u64*)&a_bf[r][0]  = (u64)aw[0] | ((u64)aw[1] << 32);
        *(u64*)&a_bf[r][4]  = (u64)aw[2] | ((u64)aw[3] << 32);
        *(u64*)&a_bf[r][8]  = (u64)aw[4] | ((u64)aw[5] << 32);
        *(u64*)&a_bf[r][12] = (u64)aw[6] | ((u64)aw[7] << 32);
        for (int i = r; i < 64 * DD; i += NTOK) {
            w1tb[i & 63][i >> 6] = (unsigned short)f2bf(w1[i]);   // w1^T
            w2tb[i & 15][i >> 4] = (unsigned short)f2bf(w2[i]);   // w2^T
        }
        if (r >= 128 && r < 192) b1_lds[r - 128] = b1[r - 128];
        if (r >= 192 && r < 208) ln2g_lds[r - 192] = ln2_g[r - 192];
        if (r >= 208 && r < 224) ln2b_lds[r - 208] = ln2_b[r - 208];
        if (r >= 224 && r < 240) b2_lds[r - 224] = b2[r - 224];
        vxT[16][r] = 0x3F80;   // ones row -> softmax denominator
    } else {
        // ---- Wa = butterfly rotations applied directly to amp (in place) ----
        float sn_l = 0.0f, cs_l = 0.0f;
        if (lane < 32) __sincosf(angles[lane], &sn_l, &cs_l);
        #pragma unroll
        for (int s = 0; s < 4; ++s) {
            const int step = 1 << s;
            #pragma unroll
            for (int p = 0; p < 8; ++p) {
                const int i = ((p >> s) << (s + 1)) | (p & (step - 1));
                const int j = i + step;
                float sn = __shfl(sn_l, s * 8 + p, 64);   // v_readlane broadcast
                float cs = __shfl(cs_l, s * 8 + p, 64);
                float vi = amp[i], vj = amp[j];
                amp[i] =  cs * vi + sn * vj;
                amp[j] = -sn * vi + cs * vj;
            }
        }
        // wa_bf pre-scaled by log2(e): P2's exp(|S|) = single native v_exp_f32
        const float L2E = 1.4426950408889634f;
        u32 ww[8];
        #pragma unroll
        for (int k = 0; k < 8; ++k)
            asm("v_cvt_pk_bf16_f32 %0, %1, %2" : "=v"(ww[k])
                : "v"(amp[2*k] * L2E), "v"(amp[2*k+1] * L2E));
        *(u64*)&wa_bf[r][0]  = (u64)ww[0] | ((u64)ww[1] << 32);
        *(u64*)&wa_bf[r][4]  = (u64)ww[2] | ((u64)ww[3] << 32);
        *(u64*)&wa_bf[r][8]  = (u64)ww[4] | ((u64)ww[5] << 32);
        *(u64*)&wa_bf[r][12] = (u64)ww[6] | ((u64)ww[7] << 32);
        #pragma unroll
        for (int d = 0; d < DD; ++d)
            vxT[d][r] = (unsigned short)f2bf(fabsf(amp[d]));
    }
    __syncthreads();
    // ======== everything below is barrier-free and per-wave independent ========

    // ---------------- P2: attention, 2-deep software pipeline -----------------
    const int ncl = (l31 < 16) ? l31 : 16;   // vx A-frag row clamp (row16 = ones)
    f32x16 Oacc = zc;
    {
        short8 waf = ld8(&wa_bf[w * 32 + l31][8 * hi]);   // B-frag: col i, k = d
        // preload ALL af A-frags (takes ds_read latency off the chain)
        short8 af[8];
        #pragma unroll
        for (int jt = 0; jt < 8; ++jt)
            af[jt] = ld8(&a_bf[jt * 32 + l31][8 * hi]);
        short8 va0 = ld8(&vxT[ncl][8 * hi]);
        short8 va1 = ld8(&vxT[ncl][16 + 8 * hi]);
        // S pipeline: S for jt+1 issues before pv-processing of jt
        f32x16 S0 = __builtin_amdgcn_mfma_f32_32x32x16_bf16(af[0], waf, zc, 0, 0, 0);
        #pragma unroll
        for (int jt = 0; jt < 8; ++jt) {
            f32x16 Sn;
            if (jt < 7)
                Sn = __builtin_amdgcn_mfma_f32_32x32x16_bf16(af[jt + 1], waf, zc, 0, 0, 0);
            short8 nva0, nva1;
            if (jt < 7) {
                nva0 = ld8(&vxT[ncl][(jt + 1) * 32 + 8 * hi]);
                nva1 = ld8(&vxT[ncl][(jt + 1) * 32 + 16 + 8 * hi]);
            }
            f32x16 pv;
            #pragma unroll
            for (int t = 0; t < 16; ++t)
                pv[t] = __builtin_amdgcn_exp2f(fabsf(S0[t]));  // exp(|S|), native
            short8 pb0, pb1;
            pack_swap16(pv, pb0, pb1);                     // B-frags: col i, k = j
            Oacc = __builtin_amdgcn_mfma_f32_32x32x16_bf16(va0, pb0, Oacc, 0, 0, 0);
            Oacc = __builtin_amdgcn_mfma_f32_32x32x16_bf16(va1, pb1, Oacc, 0, 0, 0);
            S0 = Sn; va0 = nva0; va1 = nva1;
        }
    }

    // ---------------- P3: residual + LN2, in-register (lane pairs) ------------
    // Oacc[8] = row 16 (hi=0) / 20 (hi=1); rows 16..31 all = l (clamped ones-row)
    const float rl = 1.0f / Oacc[8];
    float o1[8];
    o1[0] = xra.x + Oacc[0] * rl;  o1[1] = xra.y + Oacc[1] * rl;
    o1[2] = xra.z + Oacc[2] * rl;  o1[3] = xra.w + Oacc[3] * rl;
    o1[4] = xrb.x + Oacc[4] * rl;  o1[5] = xrb.y + Oacc[5] * rl;
    o1[6] = xrb.z + Oacc[6] * rl;  o1[7] = xrb.w + Oacc[7] * rl;

    float s8 = 0.0f;
    #pragma unroll
    for (int t = 0; t < 8; ++t) s8 += o1[t];
    float mu2 = (s8 + __shfl_xor(s8, 32, 64)) * (1.0f / DD);
    float v8 = 0.0f;
    #pragma unroll
    for (int t = 0; t < 8; ++t) { float dv = o1[t] - mu2; v8 += dv * dv; }
    float var2 = (v8 + __shfl_xor(v8, 32, 64)) * (1.0f / DD);
    float rs2 = 1.0f / sqrtf(var2 + 1e-5f);

    const float4 g0v = *(const float4*)&ln2g_lds[4 * hi];
    const float4 g1v = *(const float4*)&ln2g_lds[8 + 4 * hi];
    const float4 bb0 = *(const float4*)&ln2b_lds[4 * hi];
    const float4 bb1 = *(const float4*)&ln2b_lds[8 + 4 * hi];
    float h[8];
    h[0] = (o1[0]-mu2)*rs2*g0v.x + bb0.x;  h[1] = (o1[1]-mu2)*rs2*g0v.y + bb0.y;
    h[2] = (o1[2]-mu2)*rs2*g0v.z + bb0.z;  h[3] = (o1[3]-mu2)*rs2*g0v.w + bb0.w;
    h[4] = (o1[4]-mu2)*rs2*g1v.x + bb1.x;  h[5] = (o1[5]-mu2)*rs2*g1v.y + bb1.y;
    h[6] = (o1[6]-mu2)*rs2*g1v.z + bb1.z;  h[7] = (o1[7]-mu2)*rs2*g1v.w + bb1.w;

    short8 hB;   // B-frag (col = token, k = d)
    {
        u32 w0, w1u, w2u, w3;
        asm("v_cvt_pk_bf16_f32 %0, %1, %2" : "=v"(w0)  : "v"(h[0]), "v"(h[1]));
        asm("v_cvt_pk_bf16_f32 %0, %1, %2" : "=v"(w1u) : "v"(h[2]), "v"(h[3]));
        asm("v_cvt_pk_bf16_f32 %0, %1, %2" : "=v"(w2u) : "v"(h[4]), "v"(h[5]));
        asm("v_cvt_pk_bf16_f32 %0, %1, %2" : "=v"(w3)  : "v"(h[6]), "v"(h[7]));
        asm("s_nop 1\n\tv_permlane32_swap_b32 %0, %1" : "+v"(w0),  "+v"(w2u));
        asm("s_nop 1\n\tv_permlane32_swap_b32 %0, %1" : "+v"(w1u), "+v"(w3));
        struct { u32 x, y, z, w; } hw{w0, w1u, w2u, w3};
        hB = __builtin_bit_cast(short8, hw);
    }

    // ---------------- P4: MLP via MFMA, both H tiles in flight ----------------
    const int dcl = (l31 < 15) ? l31 : 15;   // w2 A-frag row clamp
    f32x16 O2 = zc;
    {
        const float4 c0 = *(const float4*)&b2_lds[4 * hi];
        const float4 c1 = *(const float4*)&b2_lds[8 + 4 * hi];
        O2[0] = c0.x; O2[1] = c0.y; O2[2] = c0.z; O2[3] = c0.w;
        O2[4] = c1.x; O2[5] = c1.y; O2[6] = c1.z; O2[7] = c1.w;
    }
    {
        f32x16 Hc0, Hc1;
        #pragma unroll
        for (int kblk = 0; kblk < 2; ++kblk) {
            const float* bp = &b1_lds[32 * kblk];
            const float4 c0 = *(const float4*)(bp + 4 * hi);
            const float4 c1 = *(const float4*)(bp + 8 + 4 * hi);
            const float4 c2 = *(const float4*)(bp + 16 + 4 * hi);
            const float4 c3 = *(const float4*)(bp + 24 + 4 * hi);
            f32x16& Hc = kblk ? Hc1 : Hc0;
            Hc[0]=c0.x; Hc[1]=c0.y; Hc[2]=c0.z; Hc[3]=c0.w;
            Hc[4]=c1.x; Hc[5]=c1.y; Hc[6]=c1.z; Hc[7]=c1.w;
            Hc[8]=c2.x; Hc[9]=c2.y; Hc[10]=c2.z; Hc[11]=c2.w;
            Hc[12]=c3.x; Hc[13]=c3.y; Hc[14]=c3.z; Hc[15]=c3.w;
        }
        short8 w1f0 = ld8(&w1tb[l31][8 * hi]);
        short8 w1f1 = ld8(&w1tb[32 + l31][8 * hi]);
        short8 w2a0 = ld8(&w2tb[dcl][8 * hi]);
        short8 w2a1 = ld8(&w2tb[dcl][16 + 8 * hi]);
        short8 w2b0 = ld8(&w2tb[dcl][32 + 8 * hi]);
        short8 w2b1 = ld8(&w2tb[dcl][48 + 8 * hi]);
        // both H tiles issue back-to-back; gelu/pack overlap their latency
        f32x16 H0 = __builtin_amdgcn_mfma_f32_32x32x16_bf16(w1f0, hB, Hc0, 0, 0, 0);
        f32x16 H1 = __builtin_amdgcn_mfma_f32_32x32x16_bf16(w1f1, hB, Hc1, 0, 0, 0);
        f32x16 gv0, gv1;
        #pragma unroll
        for (int t = 0; t < 16; ++t) gv0[t] = gelu_erf(H0[t]);
        short8 ga0, ga1;
        pack_swap16(gv0, ga0, ga1);
        #pragma unroll
        for (int t = 0; t < 16; ++t) gv1[t] = gelu_erf(H1[t]);
        short8 gb0, gb1;
        pack_swap16(gv1, gb0, gb1);
        O2 = __builtin_amdgcn_mfma_f32_32x32x16_bf16(w2a0, ga0, O2, 0, 0, 0);
        O2 = __builtin_amdgcn_mfma_f32_32x32x16_bf16(w2a1, ga1, O2, 0, 0, 0);
        O2 = __builtin_amdgcn_mfma_f32_32x32x16_bf16(w2b0, gb0, O2, 0, 0, 0);
        O2 = __builtin_amdgcn_mfma_f32_32x32x16_bf16(w2b1, gb1, O2, 0, 0, 0);
    }

    // ---------------- P5: out = o1 + O2 (+b2 already in O2), direct store -----
    {
        float* orow = out + ((size_t)b * NTOK + 32 * w + l31) * DD;
        float4 oa, ob;
        oa.x = o1[0] + O2[0]; oa.y = o1[1] + O2[1];
        oa.z = o1[2] + O2[2]; oa.w = o1[3] + O2[3];
        ob.x = o1[4] + O2[4]; ob.y = o1[5] + O2[5];
        ob.z = o1[6] + O2[6]; ob.w = o1[7] + O2[7];
        *(float4*)(orow + 4 * hi) = oa;
        *(float4*)(orow + 8 + 4 * hi) = ob;
    }
}

extern "C" void kernel_launch(void* const* d_in, const int* in_sizes, int n_in,
                              void* d_out, int out_size, void* d_ws, size_t ws_size,
                              hipStream_t stream) {
    const float* x     = (const float*)d_in[0];
    const float* ln1_g = (const float*)d_in[1];
    const float* ln1_b = (const float*)d_in[2];
    const float* ang   = (const float*)d_in[3];
    const float* ln2_g = (const float*)d_in[4];
    const float* ln2_b = (const float*)d_in[5];
    const float* w1    = (const float*)d_in[6];
    const float* b1    = (const float*)d_in[7];
    const float* w2    = (const float*)d_in[8];
    const float* b2    = (const float*)d_in[9];
    float* out = (float*)d_out;

    const int B = in_sizes[0] / (NTOK * DD);
    hipLaunchKernelGGL(qab_kernel, dim3(B), dim3(BDIM), 0, stream,
                       x, ln1_g, ln1_b, ang, ln2_g, ln2_b, w1, b1, w2, b2, out);
}

// Round 18
// 18.185 us; speedup vs baseline: 1.3863x; 1.0764x over previous
//
#include <hip/hip_runtime.h>
#include <math.h>

#define NTOK 256
#define DD 16
#define BDIM 512

typedef short short8 __attribute__((ext_vector_type(8)));
typedef float f32x16 __attribute__((ext_vector_type(16)));
typedef float v2f __attribute__((ext_vector_type(2)));
typedef unsigned int u32;
typedef unsigned long long u64;
#define FMA2 __builtin_elementwise_fma

__device__ __forceinline__ u32 f2bf(float f) {
    u32 u = __float_as_uint(f);
    u += 0x7FFFu + ((u >> 16) & 1u);
    return u >> 16;
}
struct U128 { u64 a, b; };
__device__ __forceinline__ short8 ld8(const unsigned short* p) {
    U128 t;
    t.a = *(const u64*)(p);
    t.b = *(const u64*)(p + 4);
    return __builtin_bit_cast(short8, t);
}
// pack 16 f32 (reg t -> k-offset pat(t,hi)=(t&3)+8*(t>>2)+4*hi) into two
// fragment short8s with k = 8*hi+e (f0: k 0..15, f1: k 16..31). HW-validated R3/R4/R6.
__device__ __forceinline__ void pack_swap16(f32x16 p, short8& f0, short8& f1) {
    u32 W00, W01, W10, W11, W20, W21, W30, W31;
    asm("v_cvt_pk_bf16_f32 %0, %1, %2" : "=v"(W00) : "v"(p[0]),  "v"(p[1]));
    asm("v_cvt_pk_bf16_f32 %0, %1, %2" : "=v"(W01) : "v"(p[2]),  "v"(p[3]));
    asm("v_cvt_pk_bf16_f32 %0, %1, %2" : "=v"(W10) : "v"(p[4]),  "v"(p[5]));
    asm("v_cvt_pk_bf16_f32 %0, %1, %2" : "=v"(W11) : "v"(p[6]),  "v"(p[7]));
    asm("v_cvt_pk_bf16_f32 %0, %1, %2" : "=v"(W20) : "v"(p[8]),  "v"(p[9]));
    asm("v_cvt_pk_bf16_f32 %0, %1, %2" : "=v"(W21) : "v"(p[10]), "v"(p[11]));
    asm("v_cvt_pk_bf16_f32 %0, %1, %2" : "=v"(W30) : "v"(p[12]), "v"(p[13]));
    asm("v_cvt_pk_bf16_f32 %0, %1, %2" : "=v"(W31) : "v"(p[14]), "v"(p[15]));
    asm("v_permlane32_swap_b32 %0, %1" : "+v"(W00), "+v"(W10));
    asm("v_permlane32_swap_b32 %0, %1" : "+v"(W01), "+v"(W11));
    asm("v_permlane32_swap_b32 %0, %1" : "+v"(W20), "+v"(W30));
    asm("v_permlane32_swap_b32 %0, %1" : "+v"(W21), "+v"(W31));
    struct { u32 x, y, z, w; } i0{W00, W01, W10, W11}, i1{W20, W21, W30, W31};
    f0 = __builtin_bit_cast(short8, i0);
    f1 = __builtin_bit_cast(short8, i1);
}
// exact-GELU (A&S 7.1.26 erf, |err|<=1.5e-7), two elements at once:
// polynomial + blend in packed f32 (v_pk_*), rcp/exp/copysign scalar.
__device__ __forceinline__ v2f gelu2(float va, float vb) {
    v2f v; v.x = va; v.y = vb;
    v2f xx = v * 0.70710678118654752f;
    float axa = fabsf(xx.x), axb = fabsf(xx.y);
    v2f t;
    t.x = __builtin_amdgcn_rcpf(__builtin_fmaf(0.3275911f, axa, 1.0f));
    t.y = __builtin_amdgcn_rcpf(__builtin_fmaf(0.3275911f, axb, 1.0f));
    v2f poly = FMA2(t, (v2f)(1.061405429f), (v2f)(-1.453152027f));
    poly = FMA2(t, poly, (v2f)(1.421413741f));
    poly = FMA2(t, poly, (v2f)(-0.284496736f));
    poly = FMA2(t, poly, (v2f)(0.254829592f));
    poly = poly * t;
    v2f E;
    E.x = __expf(-axa * axa);
    E.y = __expf(-axb * axb);
    v2f r = FMA2(-poly, E, (v2f)(1.0f));
    v2f e2;
    e2.x = copysignf(r.x, xx.x);
    e2.y = copysignf(r.y, xx.y);
    v2f hv = v * 0.5f;
    return FMA2(hv, e2, hv);
}

__global__ __launch_bounds__(BDIM, 4) void qab_kernel(
    const float* __restrict__ x,
    const float* __restrict__ ln1_g, const float* __restrict__ ln1_b,
    const float* __restrict__ angles,
    const float* __restrict__ ln2_g, const float* __restrict__ ln2_b,
    const float* __restrict__ w1, const float* __restrict__ b1,
    const float* __restrict__ w2, const float* __restrict__ b2,
    float* __restrict__ out)
{
    __shared__ alignas(16) unsigned short a_bf[NTOK][20];   // amplitudes bf16
    __shared__ alignas(16) unsigned short wa_bf[NTOK][20];  // log2e * Wa bf16
    __shared__ alignas(16) unsigned short vxT[17][268];     // |Wa|^T + ones row
    __shared__ alignas(16) unsigned short w1tb[64][20];     // w1^T bf16 [k][e]
    __shared__ alignas(16) unsigned short w2tb[16][68];     // w2^T bf16 [d][k]
    __shared__ alignas(16) float b1_lds[64];
    __shared__ alignas(16) float ln2g_lds[DD];
    __shared__ alignas(16) float ln2b_lds[DD];
    __shared__ alignas(16) float b2_lds[DD];

    const int b    = blockIdx.x;
    const int tid  = threadIdx.x;
    const int r    = tid & (NTOK - 1);
    const int q    = tid >> 8;
    const int w    = tid >> 6;
    const int l31  = tid & 31;
    const int hi   = (tid >> 5) & 1;
    const int lane = tid & 63;

    // issue residual-x loads early (row = my attention lane-row)
    const float* xres = x + ((size_t)b * NTOK + 32 * w + l31) * DD;
    const float4 xra = *(const float4*)(xres + 4 * hi);
    const float4 xrb = *(const float4*)(xres + 8 + 4 * hi);

    f32x16 zc;
    #pragma unroll
    for (int t = 0; t < 16; ++t) zc[t] = 0.0f;

    // ---------------- P0: LN1 + amp chain (ALL threads; row r redundant x2) ---
    float amp[DD];
    {
        const float* xrow = x + ((size_t)b * NTOK + r) * DD;
        float xr[DD];
        #pragma unroll
        for (int qq = 0; qq < 4; ++qq) {
            float4 v = ((const float4*)xrow)[qq];
            xr[4*qq+0] = v.x; xr[4*qq+1] = v.y; xr[4*qq+2] = v.z; xr[4*qq+3] = v.w;
        }
        float mu = 0.0f;
        #pragma unroll
        for (int d = 0; d < DD; ++d) mu += xr[d];
        mu *= (1.0f / DD);
        float var = 0.0f;
        #pragma unroll
        for (int d = 0; d < DD; ++d) { float dv = xr[d] - mu; var += dv * dv; }
        var *= (1.0f / DD);
        float rs = 1.0f / sqrtf(var + 1e-5f);
        float inp[DD];
        #pragma unroll
        for (int d = 0; d < DD; ++d)
            inp[d] = ((xr[d] - mu) * rs * ln1_g[d] + ln1_b[d]) * 0.5f;

        // Spherical decomposition reconstructs its input; track prefix^2 only.
        float P = 1.0f;
        #pragma unroll
        for (int i = 0; i < DD - 1; ++i) {
            float v = inp[i];
            float v2 = v * v;
            bool ok = v2 <= P;
            amp[i] = ok ? v : __builtin_amdgcn_sqrtf(P);
            P = ok ? __builtin_fmaf(-v, v, P) : 0.0f;
        }
        amp[DD - 1] = __builtin_amdgcn_sqrtf(P);
    }

    if (q == 0) {
        // ---- write a_bf + stage weights/consts ----
        u32 aw[8];
        #pragma unroll
        for (int k = 0; k < 8; ++k)
            asm("v_cvt_pk_bf16_f32 %0, %1, %2" : "=v"(aw[k]) : "v"(amp[2*k]), "v"(amp[2*k+1]));
        *(u64*)&a_bf[r][0]  = (u64)aw[0] | ((u64)aw[1] << 32);
        *(u64*)&a_bf[r][4]  = (u64)aw[2] | ((u64)aw[3] << 32);
        *(u64*)&a_bf[r][8]  = (u64)aw[4] | ((u64)aw[5] << 32);
        *(u64*)&a_bf[r][12] = (u64)aw[6] | ((u64)aw[7] << 32);
        for (int i = r; i < 64 * DD; i += NTOK) {
            w1tb[i & 63][i >> 6] = (unsigned short)f2bf(w1[i]);   // w1^T
            w2tb[i & 15][i >> 4] = (unsigned short)f2bf(w2[i]);   // w2^T
        }
        if (r >= 128 && r < 192) b1_lds[r - 128] = b1[r - 128];
        if (r >= 192 && r < 208) ln2g_lds[r - 192] = ln2_g[r - 192];
        if (r >= 208 && r < 224) ln2b_lds[r - 208] = ln2_b[r - 208];
        if (r >= 224 && r < 240) b2_lds[r - 224] = b2[r - 224];
        vxT[16][r] = 0x3F80;   // ones row -> softmax denominator
    } else {
        // ---- Wa = butterfly rotations applied directly to amp (in place) ----
        float sn_l = 0.0f, cs_l = 0.0f;
        if (lane < 32) __sincosf(angles[lane], &sn_l, &cs_l);
        #pragma unroll
        for (int s = 0; s < 4; ++s) {
            const int step = 1 << s;
            #pragma unroll
            for (int p = 0; p < 8; ++p) {
                const int i = ((p >> s) << (s + 1)) | (p & (step - 1));
                const int j = i + step;
                float sn = __shfl(sn_l, s * 8 + p, 64);   // v_readlane broadcast
                float cs = __shfl(cs_l, s * 8 + p, 64);
                float vi = amp[i], vj = amp[j];
                amp[i] =  cs * vi + sn * vj;
                amp[j] = -sn * vi + cs * vj;
            }
        }
        // wa_bf pre-scaled by log2(e): P2's exp(|S|) = single native v_exp_f32
        const float L2E = 1.4426950408889634f;
        u32 ww[8];
        #pragma unroll
        for (int k = 0; k < 8; ++k)
            asm("v_cvt_pk_bf16_f32 %0, %1, %2" : "=v"(ww[k])
                : "v"(amp[2*k] * L2E), "v"(amp[2*k+1] * L2E));
        *(u64*)&wa_bf[r][0]  = (u64)ww[0] | ((u64)ww[1] << 32);
        *(u64*)&wa_bf[r][4]  = (u64)ww[2] | ((u64)ww[3] << 32);
        *(u64*)&wa_bf[r][8]  = (u64)ww[4] | ((u64)ww[5] << 32);
        *(u64*)&wa_bf[r][12] = (u64)ww[6] | ((u64)ww[7] << 32);
        #pragma unroll
        for (int d = 0; d < DD; ++d)
            vxT[d][r] = (unsigned short)f2bf(fabsf(amp[d]));
    }
    __syncthreads();
    // ======== everything below is barrier-free and per-wave independent ========

    // ---------------- P2: attention, 2-deep software pipeline -----------------
    const int ncl = (l31 < 16) ? l31 : 16;   // vx A-frag row clamp (row16 = ones)
    f32x16 Oacc = zc;
    {
        short8 waf = ld8(&wa_bf[w * 32 + l31][8 * hi]);   // B-frag: col i, k = d
        // preload ALL af A-frags (takes ds_read latency off the chain)
        short8 af[8];
        #pragma unroll
        for (int jt = 0; jt < 8; ++jt)
            af[jt] = ld8(&a_bf[jt * 32 + l31][8 * hi]);
        short8 va0 = ld8(&vxT[ncl][8 * hi]);
        short8 va1 = ld8(&vxT[ncl][16 + 8 * hi]);
        // S pipeline: S for jt+1 issues before pv-processing of jt
        f32x16 S0 = __builtin_amdgcn_mfma_f32_32x32x16_bf16(af[0], waf, zc, 0, 0, 0);
        #pragma unroll
        for (int jt = 0; jt < 8; ++jt) {
            f32x16 Sn;
            if (jt < 7)
                Sn = __builtin_amdgcn_mfma_f32_32x32x16_bf16(af[jt + 1], waf, zc, 0, 0, 0);
            short8 nva0, nva1;
            if (jt < 7) {
                nva0 = ld8(&vxT[ncl][(jt + 1) * 32 + 8 * hi]);
                nva1 = ld8(&vxT[ncl][(jt + 1) * 32 + 16 + 8 * hi]);
            }
            f32x16 pv;
            #pragma unroll
            for (int t = 0; t < 16; ++t)
                pv[t] = __builtin_amdgcn_exp2f(fabsf(S0[t]));  // exp(|S|), native
            short8 pb0, pb1;
            pack_swap16(pv, pb0, pb1);                     // B-frags: col i, k = j
            Oacc = __builtin_amdgcn_mfma_f32_32x32x16_bf16(va0, pb0, Oacc, 0, 0, 0);
            Oacc = __builtin_amdgcn_mfma_f32_32x32x16_bf16(va1, pb1, Oacc, 0, 0, 0);
            S0 = Sn; va0 = nva0; va1 = nva1;
        }
    }

    // ---------------- P3: residual + LN2, in-register (lane pairs) ------------
    // Oacc[8] = row 16 (hi=0) / 20 (hi=1); rows 16..31 all = l (clamped ones-row)
    const float rl = 1.0f / Oacc[8];
    float o1[8];
    o1[0] = xra.x + Oacc[0] * rl;  o1[1] = xra.y + Oacc[1] * rl;
    o1[2] = xra.z + Oacc[2] * rl;  o1[3] = xra.w + Oacc[3] * rl;
    o1[4] = xrb.x + Oacc[4] * rl;  o1[5] = xrb.y + Oacc[5] * rl;
    o1[6] = xrb.z + Oacc[6] * rl;  o1[7] = xrb.w + Oacc[7] * rl;

    float s8 = 0.0f;
    #pragma unroll
    for (int t = 0; t < 8; ++t) s8 += o1[t];
    float mu2 = (s8 + __shfl_xor(s8, 32, 64)) * (1.0f / DD);
    float v8 = 0.0f;
    #pragma unroll
    for (int t = 0; t < 8; ++t) { float dv = o1[t] - mu2; v8 += dv * dv; }
    float var2 = (v8 + __shfl_xor(v8, 32, 64)) * (1.0f / DD);
    float rs2 = 1.0f / sqrtf(var2 + 1e-5f);

    const float4 g0v = *(const float4*)&ln2g_lds[4 * hi];
    const float4 g1v = *(const float4*)&ln2g_lds[8 + 4 * hi];
    const float4 bb0 = *(const float4*)&ln2b_lds[4 * hi];
    const float4 bb1 = *(const float4*)&ln2b_lds[8 + 4 * hi];
    float h[8];
    h[0] = (o1[0]-mu2)*rs2*g0v.x + bb0.x;  h[1] = (o1[1]-mu2)*rs2*g0v.y + bb0.y;
    h[2] = (o1[2]-mu2)*rs2*g0v.z + bb0.z;  h[3] = (o1[3]-mu2)*rs2*g0v.w + bb0.w;
    h[4] = (o1[4]-mu2)*rs2*g1v.x + bb1.x;  h[5] = (o1[5]-mu2)*rs2*g1v.y + bb1.y;
    h[6] = (o1[6]-mu2)*rs2*g1v.z + bb1.z;  h[7] = (o1[7]-mu2)*rs2*g1v.w + bb1.w;

    short8 hB;   // B-frag (col = token, k = d)
    {
        u32 w0, w1u, w2u, w3;
        asm("v_cvt_pk_bf16_f32 %0, %1, %2" : "=v"(w0)  : "v"(h[0]), "v"(h[1]));
        asm("v_cvt_pk_bf16_f32 %0, %1, %2" : "=v"(w1u) : "v"(h[2]), "v"(h[3]));
        asm("v_cvt_pk_bf16_f32 %0, %1, %2" : "=v"(w2u) : "v"(h[4]), "v"(h[5]));
        asm("v_cvt_pk_bf16_f32 %0, %1, %2" : "=v"(w3)  : "v"(h[6]), "v"(h[7]));
        asm("s_nop 1\n\tv_permlane32_swap_b32 %0, %1" : "+v"(w0),  "+v"(w2u));
        asm("s_nop 1\n\tv_permlane32_swap_b32 %0, %1" : "+v"(w1u), "+v"(w3));
        struct { u32 x, y, z, w; } hw{w0, w1u, w2u, w3};
        hB = __builtin_bit_cast(short8, hw);
    }

    // ---------------- P4: MLP via MFMA, both H tiles in flight ----------------
    const int dcl = (l31 < 15) ? l31 : 15;   // w2 A-frag row clamp
    f32x16 O2 = zc;
    {
        const float4 c0 = *(const float4*)&b2_lds[4 * hi];
        const float4 c1 = *(const float4*)&b2_lds[8 + 4 * hi];
        O2[0] = c0.x; O2[1] = c0.y; O2[2] = c0.z; O2[3] = c0.w;
        O2[4] = c1.x; O2[5] = c1.y; O2[6] = c1.z; O2[7] = c1.w;
    }
    {
        f32x16 Hc0, Hc1;
        #pragma unroll
        for (int kblk = 0; kblk < 2; ++kblk) {
            const float* bp = &b1_lds[32 * kblk];
            const float4 c0 = *(const float4*)(bp + 4 * hi);
            const float4 c1 = *(const float4*)(bp + 8 + 4 * hi);
            const float4 c2 = *(const float4*)(bp + 16 + 4 * hi);
            const float4 c3 = *(const float4*)(bp + 24 + 4 * hi);
            f32x16& Hc = kblk ? Hc1 : Hc0;
            Hc[0]=c0.x; Hc[1]=c0.y; Hc[2]=c0.z; Hc[3]=c0.w;
            Hc[4]=c1.x; Hc[5]=c1.y; Hc[6]=c1.z; Hc[7]=c1.w;
            Hc[8]=c2.x; Hc[9]=c2.y; Hc[10]=c2.z; Hc[11]=c2.w;
            Hc[12]=c3.x; Hc[13]=c3.y; Hc[14]=c3.z; Hc[15]=c3.w;
        }
        short8 w1f0 = ld8(&w1tb[l31][8 * hi]);
        short8 w1f1 = ld8(&w1tb[32 + l31][8 * hi]);
        short8 w2a0 = ld8(&w2tb[dcl][8 * hi]);
        short8 w2a1 = ld8(&w2tb[dcl][16 + 8 * hi]);
        short8 w2b0 = ld8(&w2tb[dcl][32 + 8 * hi]);
        short8 w2b1 = ld8(&w2tb[dcl][48 + 8 * hi]);
        // both H tiles issue back-to-back; gelu/pack overlap their latency
        f32x16 H0 = __builtin_amdgcn_mfma_f32_32x32x16_bf16(w1f0, hB, Hc0, 0, 0, 0);
        f32x16 H1 = __builtin_amdgcn_mfma_f32_32x32x16_bf16(w1f1, hB, Hc1, 0, 0, 0);
        f32x16 gv0, gv1;
        #pragma unroll
        for (int t = 0; t < 16; t += 2) {
            v2f g = gelu2(H0[t], H0[t+1]);
            gv0[t] = g.x; gv0[t+1] = g.y;
        }
        short8 ga0, ga1;
        pack_swap16(gv0, ga0, ga1);
        #pragma unroll
        for (int t = 0; t < 16; t += 2) {
            v2f g = gelu2(H1[t], H1[t+1]);
            gv1[t] = g.x; gv1[t+1] = g.y;
        }
        short8 gb0, gb1;
        pack_swap16(gv1, gb0, gb1);
        O2 = __builtin_amdgcn_mfma_f32_32x32x16_bf16(w2a0, ga0, O2, 0, 0, 0);
        O2 = __builtin_amdgcn_mfma_f32_32x32x16_bf16(w2a1, ga1, O2, 0, 0, 0);
        O2 = __builtin_amdgcn_mfma_f32_32x32x16_bf16(w2b0, gb0, O2, 0, 0, 0);
        O2 = __builtin_amdgcn_mfma_f32_32x32x16_bf16(w2b1, gb1, O2, 0, 0, 0);
    }

    // ---------------- P5: out = o1 + O2 (+b2 already in O2), direct store -----
    {
        float* orow = out + ((size_t)b * NTOK + 32 * w + l31) * DD;
        float4 oa, ob;
        oa.x = o1[0] + O2[0]; oa.y = o1[1] + O2[1];
        oa.z = o1[2] + O2[2]; oa.w = o1[3] + O2[3];
        ob.x = o1[4] + O2[4]; ob.y = o1[5] + O2[5];
        ob.z = o1[6] + O2[6]; ob.w = o1[7] + O2[7];
        *(float4*)(orow + 4 * hi) = oa;
        *(float4*)(orow + 8 + 4 * hi) = ob;
    }
}

extern "C" void kernel_launch(void* const* d_in, const int* in_sizes, int n_in,
                              void* d_out, int out_size, void* d_ws, size_t ws_size,
                              hipStream_t stream) {
    const float* x     = (const float*)d_in[0];
    const float* ln1_g = (const float*)d_in[1];
    const float* ln1_b = (const float*)d_in[2];
    const float* ang   = (const float*)d_in[3];
    const float* ln2_g = (const float*)d_in[4];
    const float* ln2_b = (const float*)d_in[5];
    const float* w1    = (const float*)d_in[6];
    const float* b1    = (const float*)d_in[7];
    const float* w2    = (const float*)d_in[8];
    const float* b2    = (const float*)d_in[9];
    float* out = (float*)d_out;

    const int B = in_sizes[0] / (NTOK * DD);
    hipLaunchKernelGGL(qab_kernel, dim3(B), dim3(BDIM), 0, stream,
                       x, ln1_g, ln1_b, ang, ln2_g, ln2_b, w1, b1, w2, b2, out);
}